// Round 9
// baseline (17947.800 us; speedup 1.0000x reference)
//
#include <hip/hip_runtime.h>
#include <hip/hip_bf16.h>
#include <cstdint>

// ---------------------------------------------------------------------------
// B=32, L=2048, E=256, H=128, C=128. Scan steps j=0..2046 (t=j+1).
// R9: scan7 — overlap the big gate matvec (ghh, h·Whc: 64K MACs, idx-
// independent) with wave0's serial sampling. R8's AGPR experiment proved
// weight-residency is NOT the lever (streaming from L2 at our occupancy is
// ~450B/cyc/CU, nearly free); the lever is the critical-path structure:
//   P1: hid_h partials (tiny)                       | bar
//   P2: wave0 score+sample+ghh[0:16) ; waves1-7 ghh[16:128)+park+prefetch | bar
//   P3: LSTM pointwise                              | bar
// All dot-product expressions verbatim from R5 (absmax 0.0 lineage).
// ---------------------------------------------------------------------------
static constexpr int BB   = 32;
static constexpr int LQ   = 2048;
static constexpr int NSTP = 2047;
static constexpr int EE   = 256;

__device__ __forceinline__ void bar_lds() {
  asm volatile("s_waitcnt lgkmcnt(0)\n\ts_barrier" ::: "memory");
}

// ---------------- Threefry-2x32 (JAX-compatible, verified R3-R8) -----------
__device__ __forceinline__ uint32_t rotl32(uint32_t x, int d) {
  return (x << d) | (x >> (32 - d));
}
__device__ __forceinline__ void tf2x32(uint32_t k0, uint32_t k1,
                                       uint32_t x0, uint32_t x1,
                                       uint32_t& o0, uint32_t& o1) {
  uint32_t ks2 = k0 ^ k1 ^ 0x1BD11BDAu;
  x0 += k0; x1 += k1;
  x0+=x1; x1=rotl32(x1,13); x1^=x0;  x0+=x1; x1=rotl32(x1,15); x1^=x0;
  x0+=x1; x1=rotl32(x1,26); x1^=x0;  x0+=x1; x1=rotl32(x1, 6); x1^=x0;
  x0+=k1; x1+=ks2+1u;
  x0+=x1; x1=rotl32(x1,17); x1^=x0;  x0+=x1; x1=rotl32(x1,29); x1^=x0;
  x0+=x1; x1=rotl32(x1,16); x1^=x0;  x0+=x1; x1=rotl32(x1,24); x1^=x0;
  x0+=ks2; x1+=k0+2u;
  x0+=x1; x1=rotl32(x1,13); x1^=x0;  x0+=x1; x1=rotl32(x1,15); x1^=x0;
  x0+=x1; x1=rotl32(x1,26); x1^=x0;  x0+=x1; x1=rotl32(x1, 6); x1^=x0;
  x0+=k0; x1+=k1+3u;
  x0+=x1; x1=rotl32(x1,17); x1^=x0;  x0+=x1; x1=rotl32(x1,29); x1^=x0;
  x0+=x1; x1=rotl32(x1,16); x1^=x0;  x0+=x1; x1=rotl32(x1,24); x1^=x0;
  x0+=k1; x1+=ks2+4u;
  x0+=x1; x1=rotl32(x1,13); x1^=x0;  x0+=x1; x1=rotl32(x1,15); x1^=x0;
  x0+=x1; x1=rotl32(x1,26); x1^=x0;  x0+=x1; x1=rotl32(x1, 6); x1^=x0;
  x0+=ks2; x1+=k0+5u;
  o0 = x0; o1 = x1;
}

__device__ __forceinline__ float sigm(float x) { return 1.0f / (1.0f + expf(-x)); }

// ---------------- prep: Whc = Wih[:,128:]+Whh; Wcomb/cbias (P1|G1 fused) ---
__global__ void prep_kernel(const float* __restrict__ Wp1,
                            const float* __restrict__ bp1,
                            const float* __restrict__ Wih,
                            const float* __restrict__ Whh,
                            const float* __restrict__ bih,
                            const float* __restrict__ bhh,
                            float* __restrict__ Whc,
                            float* __restrict__ Wcomb,
                            float* __restrict__ cbias) {
  int tid = blockIdx.x * blockDim.x + threadIdx.x;
  int nt  = gridDim.x * blockDim.x;
  for (int p = tid; p < 512 * 128; p += nt) {
    int g = p >> 7, e = p & 127;
    Whc[p] = Wih[g * 256 + 128 + e] + Whh[p];
  }
  for (int p = tid; p < 640 * 128; p += nt) {
    int n = p >> 7, e = p & 127;
    Wcomb[p] = (n < 128) ? Wp1[n * 256 + e] : Wih[(n - 128) * 256 + e];
  }
  for (int n = tid; n < 640; n += nt)
    cbias[n] = (n < 128) ? bp1[n] : (bih[n - 128] + bhh[n - 128]);
}

// ---------------- precompute gumbel perturbations pg[j][b*6+k] -------------
__global__ void gumbel_kernel(float* __restrict__ pg) {
  int idx = blockIdx.x * blockDim.x + threadIdx.x;
  if (idx >= NSTP * 192) return;
  int j = idx / 192, r = idx % 192;
  uint32_t a0, a1, y0, y1;
  tf2x32(0u, 42u, 0u, (uint32_t)j, a0, a1);
  tf2x32(a0, a1, 0u, (uint32_t)r, y0, y1);
  uint32_t bits = y0 ^ y1;
  float f = __uint_as_float((bits >> 9) | 0x3f800000u) - 1.0f;
  float u = fmaxf(f, 1.17549435e-38f);
  double g = -log(-log((double)u));
  pg[idx] = (float)g;
}

// ---------------- fp32 GEMM (unchanged) ------------------------------------
#define TM 128
#define TN 128
#define TKK 8
template <int MODE>
__global__ __launch_bounds__(256) void gemm_kernel(
    const float* __restrict__ A, const float* __restrict__ Bm, int ldb,
    const float* __restrict__ bias, float* __restrict__ C, int ldc,
    int M, int K, int relu, int NS, int c0) {
  int m0 = blockIdx.x * TM;
  int n0 = blockIdx.y * TN;
  int tid = threadIdx.x;
  __shared__ float As[TKK][TM + 4];
  __shared__ float Bs[TKK][TN + 4];

  int srow = tid >> 1;
  int skq  = (tid & 1) * 4;
  int gm   = m0 + srow;
  bool mvalid = gm < M;
  const float* Arow;
  if (MODE == 1) {
    int gmc = mvalid ? gm : 0;
    int bb = gmc / NS, cs = gmc % NS;
    Arow = A + (size_t)(bb * (LQ + 2) + c0 + cs + 2) * EE;
  } else {
    Arow = A + (size_t)gm * K;
  }
  const float* Brow = Bm + (size_t)(n0 + srow) * ldb;

  float acc[8][8] = {};
  int tm = (tid >> 4) * 8;
  int tn = (tid & 15) * 8;

  for (int k0 = 0; k0 < K; k0 += TKK) {
    float4 av = mvalid ? *(const float4*)(Arow + k0 + skq)
                       : make_float4(0.f, 0.f, 0.f, 0.f);
    float4 bv = *(const float4*)(Brow + k0 + skq);
    __syncthreads();
    As[skq + 0][srow] = av.x; As[skq + 1][srow] = av.y;
    As[skq + 2][srow] = av.z; As[skq + 3][srow] = av.w;
    Bs[skq + 0][srow] = bv.x; Bs[skq + 1][srow] = bv.y;
    Bs[skq + 2][srow] = bv.z; Bs[skq + 3][srow] = bv.w;
    __syncthreads();
#pragma unroll
    for (int kk = 0; kk < TKK; kk++) {
      float4 a0 = *(const float4*)&As[kk][tm];
      float4 a1 = *(const float4*)&As[kk][tm + 4];
      float4 b0 = *(const float4*)&Bs[kk][tn];
      float4 b1 = *(const float4*)&Bs[kk][tn + 4];
      float aa[8] = {a0.x, a0.y, a0.z, a0.w, a1.x, a1.y, a1.z, a1.w};
      float bb2[8] = {b0.x, b0.y, b0.z, b0.w, b1.x, b1.y, b1.z, b1.w};
#pragma unroll
      for (int i = 0; i < 8; i++)
#pragma unroll
        for (int jx = 0; jx < 8; jx++) acc[i][jx] += aa[i] * bb2[jx];
    }
  }
#pragma unroll
  for (int i = 0; i < 8; i++) {
    int gm2 = m0 + tm + i;
    if (gm2 >= M) break;
#pragma unroll
    for (int jx = 0; jx < 8; jx++) {
      int gn = n0 + tn + jx;
      float v = acc[i][jx] + bias[gn];
      if (relu) v = fmaxf(v, 0.f);
      C[(size_t)gm2 * ldc + gn] = v;
    }
  }
}

// ---------------- ghh: 4 gate rows (gb, gb+128, gb+256, gb+384), quarter q -
// Expression tree verbatim from R5's phase A (bit-exact lineage).
__device__ __forceinline__ void ghh_rows(int q, int gb,
                                         const float* __restrict__ Whc,
                                         const float* h_pad, float* ghh_s) {
  const float4* hp4 = (const float4*)(h_pad + q * 36);
  const float4* a0 = (const float4*)(Whc + ((size_t)gb + 0) * 128 + q * 32);
  const float4* a1 = (const float4*)(Whc + ((size_t)gb + 128) * 128 + q * 32);
  const float4* a2 = (const float4*)(Whc + ((size_t)gb + 256) * 128 + q * 32);
  const float4* a3 = (const float4*)(Whc + ((size_t)gb + 384) * 128 + q * 32);
  float p0 = 0.f, p1 = 0.f, p2 = 0.f, p3 = 0.f;
#pragma unroll
  for (int i = 0; i < 8; i++) {
    float4 hv = hp4[i];
    float4 a = a0[i];
    p0 += a.x * hv.x + a.y * hv.y + a.z * hv.z + a.w * hv.w;
    a = a1[i];
    p1 += a.x * hv.x + a.y * hv.y + a.z * hv.z + a.w * hv.w;
    a = a2[i];
    p2 += a.x * hv.x + a.y * hv.y + a.z * hv.z + a.w * hv.w;
    a = a3[i];
    p3 += a.x * hv.x + a.y * hv.y + a.z * hv.z + a.w * hv.w;
  }
  p0 += __shfl_xor(p0, 1); p0 += __shfl_xor(p0, 2);
  p1 += __shfl_xor(p1, 1); p1 += __shfl_xor(p1, 2);
  p2 += __shfl_xor(p2, 1); p2 += __shfl_xor(p2, 2);
  p3 += __shfl_xor(p3, 1); p3 += __shfl_xor(p3, 2);
  if (q == 0) {
    ghh_s[gb] = p0; ghh_s[128 + gb] = p1;
    ghh_s[256 + gb] = p2; ghh_s[384 + gb] = p3;
  }
}

// ---------------- scan v7: ghh overlapped with sampling --------------------
// exf rows per (b,cs): 6 x [p1(128) | g1(512)] = 3840 floats.
// state: h[32*128] | c[32*128] | lp[32]
__global__ __launch_bounds__(512, 2) void scan7_kernel(
    const float* __restrict__ exf, const float* __restrict__ pg,
    const int* __restrict__ mask, const int* __restrict__ length,
    const float* __restrict__ Wp1, const float* __restrict__ Wp2,
    const float* __restrict__ bp2, const float* __restrict__ Whc,
    float* __restrict__ state, float* __restrict__ out,
    int c0, int NS, int init) {
  const int b = blockIdx.x;
  const int tid = threadIdx.x;
  const int q = tid & 3;        // h-quarter for dots
  const int gb = tid >> 2;      // 0..127

  __shared__ float EXF[2][3840];
  __shared__ float h_pad[144];      // quarters at stride 36 (bank-spread)
  __shared__ float hh_s[128];
  __shared__ float ghh_s[512];
  __shared__ float scv[8];
  __shared__ float wp2_lds[128];
  __shared__ float gum_lds[2][8];
  __shared__ int   msk_lds[2][8];
  __shared__ int   idx_s;
  __shared__ char  idxb[2048];

  const float bp2v = bp2[0];
  const int len_b = length[b];

  float c_r = 0.f, lp_r = 0.f;
  if (tid < 144) h_pad[tid] = 0.f;
  if (tid < 128) {
    if (!init) h_pad[(tid >> 5) * 36 + (tid & 31)] = state[b * 128 + tid];
    c_r = init ? 0.f : state[4096 + b * 128 + tid];
    wp2_lds[tid] = Wp2[tid];
  }
  if (tid == 0) lp_r = init ? 0.f : state[8192 + b];

  // ---- prologue: stage step 0; prefetch step 1 into regs
  float4 pf0, pf1, pf2;
  float pfg = 0.f; int pfm = 0;
  {
    const float4* e0 = (const float4*)(exf + (size_t)b * NS * 3840);
    ((float4*)EXF[0])[tid] = e0[tid];
    if (tid < 448) ((float4*)EXF[0])[512 + tid] = e0[512 + tid];
    if (tid < 6) {
      gum_lds[0][tid] = pg[(size_t)c0 * 192 + b * 6 + tid];
      msk_lds[0][tid] = mask[((size_t)b * LQ + c0 + 1) * 6 + tid];
    }
    int cs1 = (NS > 1) ? 1 : 0;
    const float4* e1 = (const float4*)(exf + ((size_t)b * NS + cs1) * 3840);
    if (tid >= 64) {
      int i0 = tid - 64;
      pf0 = e1[i0];
      pf1 = e1[448 + i0];
      if (tid < 128) pf2 = e1[896 + i0];
    }
    if (tid >= 384 && tid < 390)
      pfg = pg[(size_t)(c0 + cs1) * 192 + b * 6 + (tid - 384)];
    if (tid >= 390 && tid < 396)
      pfm = mask[((size_t)b * LQ + c0 + cs1 + 1) * 6 + (tid - 390)];
  }
  bar_lds();

  for (int cs = 0; cs < NS; ++cs) {
    const int buf = cs & 1;
    const int nb = buf ^ 1;

    // ---- P1: hid_h partials only (small) ------------------------------
    {
      const float4* hp4 = (const float4*)(h_pad + q * 36);
      const float4* s0 = (const float4*)(Wp1 + (size_t)gb * 256 + 128 + q * 32);
      float hidp = 0.f;
#pragma unroll
      for (int i = 0; i < 8; i++) {
        float4 hv = hp4[i];
        float4 w = s0[i];
        hidp += w.x * hv.x + w.y * hv.y + w.z * hv.z + w.w * hv.w;
      }
      hidp += __shfl_xor(hidp, 1); hidp += __shfl_xor(hidp, 2);
      if (q == 0) hh_s[gb] = hidp;
    }
    bar_lds();

    // ---- P2: wave0 scores+samples then ghh[0:16);
    //          waves 1-7: ghh[16:128) + park + prefetch -----------------
    if (tid < 64) {
      const int k = tid >> 3, r = tid & 7;
      float s = 0.f;
      if (k < 6) {
        const float* pb = &EXF[buf][k * 640 + r * 16];
        const float* hb = &hh_s[r * 16];
        const float* wb = &wp2_lds[r * 16];
#pragma unroll
        for (int ii = 0; ii < 4; ii++) {
          float4 p = *(const float4*)(pb + ii * 4);
          float4 hh = *(const float4*)(hb + ii * 4);
          float4 w = *(const float4*)(wb + ii * 4);
          s += fmaxf(p.x + hh.x, 0.f) * w.x + fmaxf(p.y + hh.y, 0.f) * w.y +
               fmaxf(p.z + hh.z, 0.f) * w.z + fmaxf(p.w + hh.w, 0.f) * w.w;
        }
      }
      s += __shfl_xor(s, 1);
      s += __shfl_xor(s, 2);
      s += __shfl_xor(s, 4);
      if (k < 6 && r == 0) scv[k] = fmaxf(s + bp2v, 0.f);
      asm volatile("s_waitcnt lgkmcnt(0)" ::: "memory");
      if (tid == 0) {
        float best = -3.4e38f, mx = -1e9f, libest = -1e9f, ssum;
        int bi = 0;
        float lgv[6];
#pragma unroll
        for (int k2 = 0; k2 < 6; k2++) {
          float lg = msk_lds[buf][k2] ? scv[k2] : -1e9f;
          float pt = gum_lds[buf][k2] + lg;
          if (pt > best) { best = pt; bi = k2; libest = lg; }
          mx = fmaxf(mx, lg);
          lgv[k2] = lg;
        }
        ssum = 0.f;
#pragma unroll
        for (int k2 = 0; k2 < 6; k2++) ssum += __expf(lgv[k2] - mx);
        float logp = libest - mx - __logf(ssum);
        if (len_b > c0 + cs + 1) lp_r += logp;
        idx_s = bi;
        idxb[cs] = (char)bi;
      }
      // wave0's share of the gate matvec (idx-independent)
      ghh_rows(q, gb, Whc, h_pad, ghh_s);
    } else {
      // big gate matvec for gb 16..127, overlapped with wave0's sampling
      ghh_rows(q, gb, Whc, h_pad, ghh_s);
      // park prefetched step data
      int i0 = tid - 64;
      ((float4*)EXF[nb])[i0] = pf0;
      ((float4*)EXF[nb])[448 + i0] = pf1;
      if (tid < 128) ((float4*)EXF[nb])[896 + i0] = pf2;
      if (tid >= 384 && tid < 390) gum_lds[nb][tid - 384] = pfg;
      if (tid >= 390 && tid < 396) msk_lds[nb][tid - 390] = pfm;
      int csp = (cs + 2 < NS) ? cs + 2 : NS - 1;
      const float4* en = (const float4*)(exf + ((size_t)b * NS + csp) * 3840);
      pf0 = en[i0];
      pf1 = en[448 + i0];
      if (tid < 128) pf2 = en[896 + i0];
      if (tid >= 384 && tid < 390)
        pfg = pg[(size_t)(c0 + csp) * 192 + b * 6 + (tid - 384)];
      if (tid >= 390 && tid < 396)
        pfm = mask[((size_t)b * LQ + c0 + csp + 1) * 6 + (tid - 390)];
    }
    bar_lds();

    // ---- P3: LSTM pointwise (tid<128) ---------------------------------
    if (tid < 128) {
      int base = idx_s * 640 + 128 + tid;
      float iv = EXF[buf][base] + ghh_s[tid];
      float fv = EXF[buf][base + 128] + ghh_s[128 + tid];
      float gg = EXF[buf][base + 256] + ghh_s[256 + tid];
      float ov = EXF[buf][base + 384] + ghh_s[384 + tid];
      float c2 = sigm(fv) * c_r + sigm(iv) * tanhf(gg);
      float h2 = sigm(ov) * tanhf(c2);
      c_r = c2;
      h_pad[(tid >> 5) * 36 + (tid & 31)] = h2;
    }
    bar_lds();
  }

  // ---- epilogue
  if (tid < 128) {
    state[b * 128 + tid] = h_pad[(tid >> 5) * 36 + (tid & 31)];
    state[4096 + b * 128 + tid] = c_r;
  }
  if (tid == 0) {
    state[8192 + b] = lp_r;
    out[b] = lp_r;
  }
  for (int i = tid; i < NS; i += 512)
    out[32 + (size_t)(c0 + i) * 32 + b] = (float)idxb[i];
}

__global__ void sentinel_kernel(float* out, int n, float val) {
  int i = blockIdx.x * blockDim.x + threadIdx.x;
  if (i < n) out[i] = val;
}

// ---------------------------------------------------------------------------
extern "C" void kernel_launch(void* const* d_in, const int* in_sizes, int n_in,
                              void* d_out, int out_size, void* d_ws,
                              size_t ws_size, hipStream_t stream) {
  const float* memory = (const float*)d_in[0];
  const int* mask = (const int*)d_in[1];     // bool delivered as int32
  const int* length = (const int*)d_in[2];
  const float* W1  = (const float*)d_in[3];
  const float* b1  = (const float*)d_in[4];
  const float* Wp1 = (const float*)d_in[5];
  const float* bp1 = (const float*)d_in[6];
  const float* Wp2 = (const float*)d_in[7];
  const float* bp2 = (const float*)d_in[8];
  const float* Wih = (const float*)d_in[9];
  const float* Whh = (const float*)d_in[10];
  const float* bih = (const float*)d_in[11];
  const float* bhh = (const float*)d_in[12];
  float* out = (float*)d_out;

  char* ws = (char*)d_ws;
  const size_t o_whc   = 0;                    // 512*128*4  = 262144
  const size_t o_wcomb = 262144;               // 640*128*4  = 327680
  const size_t o_cbias = 589824;               // 640*4      = 2560
  const size_t o_state = 592384;               // -> pad 36864
  const size_t o_pg    = 629248;               // 2047*192*4 = 1572096
  const size_t o_buf   = 2201344;              // chunk buffers

  const size_t per_cs = 32ull * (768 + 3840) * 4;  // 589824
  long long usable = (long long)ws_size - (long long)o_buf;
  int CS = (usable > 0) ? (int)(usable / (long long)per_cs) : 0;
  if (CS > NSTP) CS = NSTP;
  if (CS < 1) {
    float val = -100000.0f - (float)(ws_size >> 20);
    sentinel_kernel<<<(out_size + 255) / 256, 256, 0, stream>>>(out, out_size, val);
    return;
  }

  float* Whc   = (float*)(ws + o_whc);
  float* Wcomb = (float*)(ws + o_wcomb);
  float* cbias = (float*)(ws + o_cbias);
  float* state = (float*)(ws + o_state);
  float* pgbuf = (float*)(ws + o_pg);

  prep_kernel<<<64, 256, 0, stream>>>(Wp1, bp1, Wih, Whh, bih, bhh,
                                      Whc, Wcomb, cbias);
  gumbel_kernel<<<(NSTP * 192 + 255) / 256, 256, 0, stream>>>(pgbuf);

  int nchunks = (NSTP + CS - 1) / CS;
  for (int c = 0; c < nchunks; ++c) {
    int c0 = c * CS;
    int NS = (c0 + CS <= NSTP) ? CS : (NSTP - c0);
    int Mcf = 32 * NS;
    int M6  = Mcf * 6;

    float* cf  = (float*)(ws + o_buf);
    float* exf = cf + (size_t)Mcf * 768;

    // cf = relu(memory_rows @ W1^T + b1): M=32*NS, N=768, K=256
    gemm_kernel<1><<<dim3((Mcf + TM - 1) / TM, 768 / TN), 256, 0, stream>>>(
        memory, W1, 256, b1, cf, 768, Mcf, 256, 1, NS, c0);
    // exf = cf6 @ Wcomb^T + cbias: M=M6, N=640 (p1|g1), K=128
    gemm_kernel<0><<<dim3((M6 + TM - 1) / TM, 640 / TN), 256, 0, stream>>>(
        cf, Wcomb, 128, cbias, exf, 640, M6, 128, 0, NS, c0);
    // scan this chunk
    scan7_kernel<<<BB, 512, 0, stream>>>(exf, pgbuf, mask, length, Wp1, Wp2,
                                         bp2, Whc, state, out, c0, NS,
                                         (c == 0) ? 1 : 0);
  }
}

// Round 10
// 7336.449 us; speedup vs baseline: 2.4464x; 2.4464x over previous
//
#include <hip/hip_runtime.h>
#include <hip/hip_bf16.h>
#include <cstdint>

// ---------------------------------------------------------------------------
// B=32, L=2048, E=256, H=128, C=128. Scan steps j=0..2046 (t=j+1).
// R10: scan8 = R5's exact 3-phase schedule at 1024 threads (16 waves,
// 4 waves/SIMD). R9's divergent-overlap spilled (VGPR 80, 4x regression);
// R5's stall is ~55% latency with only 2 waves/SIMD — double the TLP.
// h is eighth-split (q=tid&7, 16 elems; gb=tid>>3); padded-stride-20 h_pad
// keeps ds_read_b128 conflict-free. Sampling wave and LSTM unchanged.
// ---------------------------------------------------------------------------
static constexpr int BB   = 32;
static constexpr int LQ   = 2048;
static constexpr int NSTP = 2047;
static constexpr int EE   = 256;

__device__ __forceinline__ void bar_lds() {
  asm volatile("s_waitcnt lgkmcnt(0)\n\ts_barrier" ::: "memory");
}

// ---------------- Threefry-2x32 (JAX-compatible, verified R3-R9) -----------
__device__ __forceinline__ uint32_t rotl32(uint32_t x, int d) {
  return (x << d) | (x >> (32 - d));
}
__device__ __forceinline__ void tf2x32(uint32_t k0, uint32_t k1,
                                       uint32_t x0, uint32_t x1,
                                       uint32_t& o0, uint32_t& o1) {
  uint32_t ks2 = k0 ^ k1 ^ 0x1BD11BDAu;
  x0 += k0; x1 += k1;
  x0+=x1; x1=rotl32(x1,13); x1^=x0;  x0+=x1; x1=rotl32(x1,15); x1^=x0;
  x0+=x1; x1=rotl32(x1,26); x1^=x0;  x0+=x1; x1=rotl32(x1, 6); x1^=x0;
  x0+=k1; x1+=ks2+1u;
  x0+=x1; x1=rotl32(x1,17); x1^=x0;  x0+=x1; x1=rotl32(x1,29); x1^=x0;
  x0+=x1; x1=rotl32(x1,16); x1^=x0;  x0+=x1; x1=rotl32(x1,24); x1^=x0;
  x0+=ks2; x1+=k0+2u;
  x0+=x1; x1=rotl32(x1,13); x1^=x0;  x0+=x1; x1=rotl32(x1,15); x1^=x0;
  x0+=x1; x1=rotl32(x1,26); x1^=x0;  x0+=x1; x1=rotl32(x1, 6); x1^=x0;
  x0+=k0; x1+=k1+3u;
  x0+=x1; x1=rotl32(x1,17); x1^=x0;  x0+=x1; x1=rotl32(x1,29); x1^=x0;
  x0+=x1; x1=rotl32(x1,16); x1^=x0;  x0+=x1; x1=rotl32(x1,24); x1^=x0;
  x0+=k1; x1+=ks2+4u;
  x0+=x1; x1=rotl32(x1,13); x1^=x0;  x0+=x1; x1=rotl32(x1,15); x1^=x0;
  x0+=x1; x1=rotl32(x1,26); x1^=x0;  x0+=x1; x1=rotl32(x1, 6); x1^=x0;
  x0+=ks2; x1+=k0+5u;
  o0 = x0; o1 = x1;
}

__device__ __forceinline__ float sigm(float x) { return 1.0f / (1.0f + expf(-x)); }

// ---------------- prep: Whc = Wih[:,128:]+Whh; Wcomb/cbias (P1|G1 fused) ---
__global__ void prep_kernel(const float* __restrict__ Wp1,
                            const float* __restrict__ bp1,
                            const float* __restrict__ Wih,
                            const float* __restrict__ Whh,
                            const float* __restrict__ bih,
                            const float* __restrict__ bhh,
                            float* __restrict__ Whc,
                            float* __restrict__ Wcomb,
                            float* __restrict__ cbias) {
  int tid = blockIdx.x * blockDim.x + threadIdx.x;
  int nt  = gridDim.x * blockDim.x;
  for (int p = tid; p < 512 * 128; p += nt) {
    int g = p >> 7, e = p & 127;
    Whc[p] = Wih[g * 256 + 128 + e] + Whh[p];
  }
  for (int p = tid; p < 640 * 128; p += nt) {
    int n = p >> 7, e = p & 127;
    Wcomb[p] = (n < 128) ? Wp1[n * 256 + e] : Wih[(n - 128) * 256 + e];
  }
  for (int n = tid; n < 640; n += nt)
    cbias[n] = (n < 128) ? bp1[n] : (bih[n - 128] + bhh[n - 128]);
}

// ---------------- precompute gumbel perturbations pg[j][b*6+k] -------------
__global__ void gumbel_kernel(float* __restrict__ pg) {
  int idx = blockIdx.x * blockDim.x + threadIdx.x;
  if (idx >= NSTP * 192) return;
  int j = idx / 192, r = idx % 192;
  uint32_t a0, a1, y0, y1;
  tf2x32(0u, 42u, 0u, (uint32_t)j, a0, a1);
  tf2x32(a0, a1, 0u, (uint32_t)r, y0, y1);
  uint32_t bits = y0 ^ y1;
  float f = __uint_as_float((bits >> 9) | 0x3f800000u) - 1.0f;
  float u = fmaxf(f, 1.17549435e-38f);
  double g = -log(-log((double)u));
  pg[idx] = (float)g;
}

// ---------------- fp32 GEMM (unchanged) ------------------------------------
#define TM 128
#define TN 128
#define TKK 8
template <int MODE>
__global__ __launch_bounds__(256) void gemm_kernel(
    const float* __restrict__ A, const float* __restrict__ Bm, int ldb,
    const float* __restrict__ bias, float* __restrict__ C, int ldc,
    int M, int K, int relu, int NS, int c0) {
  int m0 = blockIdx.x * TM;
  int n0 = blockIdx.y * TN;
  int tid = threadIdx.x;
  __shared__ float As[TKK][TM + 4];
  __shared__ float Bs[TKK][TN + 4];

  int srow = tid >> 1;
  int skq  = (tid & 1) * 4;
  int gm   = m0 + srow;
  bool mvalid = gm < M;
  const float* Arow;
  if (MODE == 1) {
    int gmc = mvalid ? gm : 0;
    int bb = gmc / NS, cs = gmc % NS;
    Arow = A + (size_t)(bb * (LQ + 2) + c0 + cs + 2) * EE;
  } else {
    Arow = A + (size_t)gm * K;
  }
  const float* Brow = Bm + (size_t)(n0 + srow) * ldb;

  float acc[8][8] = {};
  int tm = (tid >> 4) * 8;
  int tn = (tid & 15) * 8;

  for (int k0 = 0; k0 < K; k0 += TKK) {
    float4 av = mvalid ? *(const float4*)(Arow + k0 + skq)
                       : make_float4(0.f, 0.f, 0.f, 0.f);
    float4 bv = *(const float4*)(Brow + k0 + skq);
    __syncthreads();
    As[skq + 0][srow] = av.x; As[skq + 1][srow] = av.y;
    As[skq + 2][srow] = av.z; As[skq + 3][srow] = av.w;
    Bs[skq + 0][srow] = bv.x; Bs[skq + 1][srow] = bv.y;
    Bs[skq + 2][srow] = bv.z; Bs[skq + 3][srow] = bv.w;
    __syncthreads();
#pragma unroll
    for (int kk = 0; kk < TKK; kk++) {
      float4 a0 = *(const float4*)&As[kk][tm];
      float4 a1 = *(const float4*)&As[kk][tm + 4];
      float4 b0 = *(const float4*)&Bs[kk][tn];
      float4 b1 = *(const float4*)&Bs[kk][tn + 4];
      float aa[8] = {a0.x, a0.y, a0.z, a0.w, a1.x, a1.y, a1.z, a1.w};
      float bb2[8] = {b0.x, b0.y, b0.z, b0.w, b1.x, b1.y, b1.z, b1.w};
#pragma unroll
      for (int i = 0; i < 8; i++)
#pragma unroll
        for (int jx = 0; jx < 8; jx++) acc[i][jx] += aa[i] * bb2[jx];
    }
  }
#pragma unroll
  for (int i = 0; i < 8; i++) {
    int gm2 = m0 + tm + i;
    if (gm2 >= M) break;
#pragma unroll
    for (int jx = 0; jx < 8; jx++) {
      int gn = n0 + tn + jx;
      float v = acc[i][jx] + bias[gn];
      if (relu) v = fmaxf(v, 0.f);
      C[(size_t)gm2 * ldc + gn] = v;
    }
  }
}

// ---------------- scan v8: R5 schedule @ 1024 threads, eighth-split --------
// exf rows per (b,cs): 6 x [p1(128) | g1(512)] = 3840 floats.
// state: h[32*128] | c[32*128] | lp[32]
// h_pad: element e at h_pad[(e>>4)*20 + (e&15)] (8 groups, stride 20).
__global__ __launch_bounds__(1024, 4) void scan8_kernel(
    const float* __restrict__ exf, const float* __restrict__ pg,
    const int* __restrict__ mask, const int* __restrict__ length,
    const float* __restrict__ Wp1, const float* __restrict__ Wp2,
    const float* __restrict__ bp2, const float* __restrict__ Whc,
    float* __restrict__ state, float* __restrict__ out,
    int c0, int NS, int init) {
  const int b = blockIdx.x;
  const int tid = threadIdx.x;
  const int q = tid & 7;        // h-eighth (16 elems) for dots
  const int gb = tid >> 3;      // 0..127

  __shared__ float EXF[2][3840];
  __shared__ float h_pad[160];      // eighths at stride 20 (bank-spread)
  __shared__ float hh_s[128];
  __shared__ float ghh_s[512];
  __shared__ float scv[8];
  __shared__ float wp2_lds[128];
  __shared__ float gum_lds[2][8];
  __shared__ int   msk_lds[2][8];
  __shared__ int   idx_s;
  __shared__ char  idxb[2048];

  const float bp2v = bp2[0];
  const int len_b = length[b];

  float c_r = 0.f, lp_r = 0.f;
  if (tid < 160) h_pad[tid] = 0.f;
  if (tid < 128) {
    if (!init) h_pad[(tid >> 4) * 20 + (tid & 15)] = state[b * 128 + tid];
    c_r = init ? 0.f : state[4096 + b * 128 + tid];
    wp2_lds[tid] = Wp2[tid];
  }
  if (tid == 0) lp_r = init ? 0.f : state[8192 + b];

  // ---- prologue: stage step 0; prefetch step 1 into regs (1 float4/thread)
  float4 pf0;
  float pfg = 0.f; int pfm = 0;
  {
    const float4* e0 = (const float4*)(exf + (size_t)b * NS * 3840);
    if (tid < 960) ((float4*)EXF[0])[tid] = e0[tid];
    if (tid < 6) {
      gum_lds[0][tid] = pg[(size_t)c0 * 192 + b * 6 + tid];
      msk_lds[0][tid] = mask[((size_t)b * LQ + c0 + 1) * 6 + tid];
    }
    int cs1 = (NS > 1) ? 1 : 0;
    const float4* e1 = (const float4*)(exf + ((size_t)b * NS + cs1) * 3840);
    if (tid >= 64) pf0 = e1[tid - 64];
    if (tid >= 1008 && tid < 1014)
      pfg = pg[(size_t)(c0 + cs1) * 192 + b * 6 + (tid - 1008)];
    if (tid >= 1014 && tid < 1020)
      pfm = mask[((size_t)b * LQ + c0 + cs1 + 1) * 6 + (tid - 1014)];
  }
  bar_lds();

  for (int cs = 0; cs < NS; ++cs) {
    const int buf = cs & 1;
    const int nb = buf ^ 1;

    // ---- P1: hid_h + ghh partials (eighth-split, 16 waves hide latency)
    {
      const float4* hp4 = (const float4*)(h_pad + q * 20);
      const float4* s0 = (const float4*)(Wp1 + (size_t)gb * 256 + 128 + q * 16);
      const float4* a0 = (const float4*)(Whc + ((size_t)gb + 0) * 128 + q * 16);
      const float4* a1 = (const float4*)(Whc + ((size_t)gb + 128) * 128 + q * 16);
      const float4* a2 = (const float4*)(Whc + ((size_t)gb + 256) * 128 + q * 16);
      const float4* a3 = (const float4*)(Whc + ((size_t)gb + 384) * 128 + q * 16);
      float hidp = 0.f, p0 = 0.f, p1 = 0.f, p2 = 0.f, p3 = 0.f;
#pragma unroll
      for (int i = 0; i < 4; i++) {
        float4 hv = hp4[i];
        float4 w = s0[i];
        hidp += w.x * hv.x + w.y * hv.y + w.z * hv.z + w.w * hv.w;
        float4 a = a0[i];
        p0 += a.x * hv.x + a.y * hv.y + a.z * hv.z + a.w * hv.w;
        a = a1[i];
        p1 += a.x * hv.x + a.y * hv.y + a.z * hv.z + a.w * hv.w;
        a = a2[i];
        p2 += a.x * hv.x + a.y * hv.y + a.z * hv.z + a.w * hv.w;
        a = a3[i];
        p3 += a.x * hv.x + a.y * hv.y + a.z * hv.z + a.w * hv.w;
      }
      hidp += __shfl_xor(hidp, 1); hidp += __shfl_xor(hidp, 2);
      hidp += __shfl_xor(hidp, 4);
      p0 += __shfl_xor(p0, 1); p0 += __shfl_xor(p0, 2); p0 += __shfl_xor(p0, 4);
      p1 += __shfl_xor(p1, 1); p1 += __shfl_xor(p1, 2); p1 += __shfl_xor(p1, 4);
      p2 += __shfl_xor(p2, 1); p2 += __shfl_xor(p2, 2); p2 += __shfl_xor(p2, 4);
      p3 += __shfl_xor(p3, 1); p3 += __shfl_xor(p3, 2); p3 += __shfl_xor(p3, 4);
      if (q == 0) {
        hh_s[gb] = hidp;
        ghh_s[gb] = p0; ghh_s[128 + gb] = p1;
        ghh_s[256 + gb] = p2; ghh_s[384 + gb] = p3;
      }
    }
    bar_lds();

    // ---- P2: wave0 scores+samples; waves 1-15 park & prefetch ----------
    if (tid < 64) {
      const int k = tid >> 3, r = tid & 7;
      float s = 0.f;
      if (k < 6) {
        const float* pb = &EXF[buf][k * 640 + r * 16];
        const float* hb = &hh_s[r * 16];
        const float* wb = &wp2_lds[r * 16];
#pragma unroll
        for (int ii = 0; ii < 4; ii++) {
          float4 p = *(const float4*)(pb + ii * 4);
          float4 hh = *(const float4*)(hb + ii * 4);
          float4 w = *(const float4*)(wb + ii * 4);
          s += fmaxf(p.x + hh.x, 0.f) * w.x + fmaxf(p.y + hh.y, 0.f) * w.y +
               fmaxf(p.z + hh.z, 0.f) * w.z + fmaxf(p.w + hh.w, 0.f) * w.w;
        }
      }
      s += __shfl_xor(s, 1);
      s += __shfl_xor(s, 2);
      s += __shfl_xor(s, 4);
      if (k < 6 && r == 0) scv[k] = fmaxf(s + bp2v, 0.f);
      asm volatile("s_waitcnt lgkmcnt(0)" ::: "memory");
      if (tid == 0) {
        float best = -3.4e38f, mx = -1e9f, libest = -1e9f, ssum;
        int bi = 0;
        float lgv[6];
#pragma unroll
        for (int k2 = 0; k2 < 6; k2++) {
          float lg = msk_lds[buf][k2] ? scv[k2] : -1e9f;
          float pt = gum_lds[buf][k2] + lg;
          if (pt > best) { best = pt; bi = k2; libest = lg; }
          mx = fmaxf(mx, lg);
          lgv[k2] = lg;
        }
        ssum = 0.f;
#pragma unroll
        for (int k2 = 0; k2 < 6; k2++) ssum += __expf(lgv[k2] - mx);
        float logp = libest - mx - __logf(ssum);
        if (len_b > c0 + cs + 1) lp_r += logp;
        idx_s = bi;
        idxb[cs] = (char)bi;
      }
    } else {
      int i0 = tid - 64;                      // 0..959: exactly one float4
      ((float4*)EXF[nb])[i0] = pf0;
      if (tid >= 1008 && tid < 1014) gum_lds[nb][tid - 1008] = pfg;
      if (tid >= 1014 && tid < 1020) msk_lds[nb][tid - 1014] = pfm;
      int csp = (cs + 2 < NS) ? cs + 2 : NS - 1;
      const float4* en = (const float4*)(exf + ((size_t)b * NS + csp) * 3840);
      pf0 = en[i0];
      if (tid >= 1008 && tid < 1014)
        pfg = pg[(size_t)(c0 + csp) * 192 + b * 6 + (tid - 1008)];
      if (tid >= 1014 && tid < 1020)
        pfm = mask[((size_t)b * LQ + c0 + csp + 1) * 6 + (tid - 1014)];
    }
    bar_lds();

    // ---- P3: LSTM pointwise (tid<128) ----------------------------------
    if (tid < 128) {
      int base = idx_s * 640 + 128 + tid;
      float iv = EXF[buf][base] + ghh_s[tid];
      float fv = EXF[buf][base + 128] + ghh_s[128 + tid];
      float gg = EXF[buf][base + 256] + ghh_s[256 + tid];
      float ov = EXF[buf][base + 384] + ghh_s[384 + tid];
      float c2 = sigm(fv) * c_r + sigm(iv) * tanhf(gg);
      float h2 = sigm(ov) * tanhf(c2);
      c_r = c2;
      h_pad[(tid >> 4) * 20 + (tid & 15)] = h2;
    }
    bar_lds();
  }

  // ---- epilogue
  if (tid < 128) {
    state[b * 128 + tid] = h_pad[(tid >> 4) * 20 + (tid & 15)];
    state[4096 + b * 128 + tid] = c_r;
  }
  if (tid == 0) {
    state[8192 + b] = lp_r;
    out[b] = lp_r;
  }
  for (int i = tid; i < NS; i += 1024)
    out[32 + (size_t)(c0 + i) * 32 + b] = (float)idxb[i];
}

__global__ void sentinel_kernel(float* out, int n, float val) {
  int i = blockIdx.x * blockDim.x + threadIdx.x;
  if (i < n) out[i] = val;
}

// ---------------------------------------------------------------------------
extern "C" void kernel_launch(void* const* d_in, const int* in_sizes, int n_in,
                              void* d_out, int out_size, void* d_ws,
                              size_t ws_size, hipStream_t stream) {
  const float* memory = (const float*)d_in[0];
  const int* mask = (const int*)d_in[1];     // bool delivered as int32
  const int* length = (const int*)d_in[2];
  const float* W1  = (const float*)d_in[3];
  const float* b1  = (const float*)d_in[4];
  const float* Wp1 = (const float*)d_in[5];
  const float* bp1 = (const float*)d_in[6];
  const float* Wp2 = (const float*)d_in[7];
  const float* bp2 = (const float*)d_in[8];
  const float* Wih = (const float*)d_in[9];
  const float* Whh = (const float*)d_in[10];
  const float* bih = (const float*)d_in[11];
  const float* bhh = (const float*)d_in[12];
  float* out = (float*)d_out;

  char* ws = (char*)d_ws;
  const size_t o_whc   = 0;                    // 512*128*4  = 262144
  const size_t o_wcomb = 262144;               // 640*128*4  = 327680
  const size_t o_cbias = 589824;               // 640*4      = 2560
  const size_t o_state = 592384;               // -> pad 36864
  const size_t o_pg    = 629248;               // 2047*192*4 = 1572096
  const size_t o_buf   = 2201344;              // chunk buffers

  const size_t per_cs = 32ull * (768 + 3840) * 4;  // 589824
  long long usable = (long long)ws_size - (long long)o_buf;
  int CS = (usable > 0) ? (int)(usable / (long long)per_cs) : 0;
  if (CS > NSTP) CS = NSTP;
  if (CS < 1) {
    float val = -100000.0f - (float)(ws_size >> 20);
    sentinel_kernel<<<(out_size + 255) / 256, 256, 0, stream>>>(out, out_size, val);
    return;
  }

  float* Whc   = (float*)(ws + o_whc);
  float* Wcomb = (float*)(ws + o_wcomb);
  float* cbias = (float*)(ws + o_cbias);
  float* state = (float*)(ws + o_state);
  float* pgbuf = (float*)(ws + o_pg);

  prep_kernel<<<64, 256, 0, stream>>>(Wp1, bp1, Wih, Whh, bih, bhh,
                                      Whc, Wcomb, cbias);
  gumbel_kernel<<<(NSTP * 192 + 255) / 256, 256, 0, stream>>>(pgbuf);

  int nchunks = (NSTP + CS - 1) / CS;
  for (int c = 0; c < nchunks; ++c) {
    int c0 = c * CS;
    int NS = (c0 + CS <= NSTP) ? CS : (NSTP - c0);
    int Mcf = 32 * NS;
    int M6  = Mcf * 6;

    float* cf  = (float*)(ws + o_buf);
    float* exf = cf + (size_t)Mcf * 768;

    // cf = relu(memory_rows @ W1^T + b1): M=32*NS, N=768, K=256
    gemm_kernel<1><<<dim3((Mcf + TM - 1) / TM, 768 / TN), 256, 0, stream>>>(
        memory, W1, 256, b1, cf, 768, Mcf, 256, 1, NS, c0);
    // exf = cf6 @ Wcomb^T + cbias: M=M6, N=640 (p1|g1), K=128
    gemm_kernel<0><<<dim3((M6 + TM - 1) / TM, 640 / TN), 256, 0, stream>>>(
        cf, Wcomb, 128, cbias, exf, 640, M6, 128, 0, NS, c0);
    // scan this chunk
    scan8_kernel<<<BB, 1024, 0, stream>>>(exf, pgbuf, mask, length, Wp1, Wp2,
                                          bp2, Whc, state, out, c0, NS,
                                          (c == 0) ? 1 : 0);
  }
}

// Round 11
// 6787.102 us; speedup vs baseline: 2.6444x; 1.0809x over previous
//
#include <hip/hip_runtime.h>
#include <hip/hip_bf16.h>
#include <cstdint>

// ---------------------------------------------------------------------------
// B=32, L=2048, E=256, H=128, C=128. Scan steps j=0..2046 (t=j+1).
// R11: scan9 — weights partially in LDS. Cost model: phase A streams 320 KB
// of weights/step through one CU (L2 ~64 B/cyc -> ~5000 cyc = measured 2.1us).
// Preload 112 KB (Wp1part + Whc rows 0..95) into 155KB dynamic LDS once per
// chunk; per-step L2 stream drops to ~208 KB and LDS serves the rest in
// parallel. Same 3-phase R5 schedule, same expression order (bit-exact).
// Fallback to R5/R7's verified scan5 if big-LDS attr is unavailable.
// ---------------------------------------------------------------------------
static constexpr int BB   = 32;
static constexpr int LQ   = 2048;
static constexpr int NSTP = 2047;
static constexpr int EE   = 256;

// dynamic-LDS float offsets (scan9)
static constexpr int oEXF  = 0;        // 2*3840
static constexpr int oHP   = 7680;     // 144 (h quarters @ stride 36)
static constexpr int oHH   = 7824;     // 128
static constexpr int oGHH  = 7952;     // 512
static constexpr int oSCV  = 8464;     // 8
static constexpr int oWP2  = 8472;     // 128
static constexpr int oGUM  = 8600;     // 2*8
static constexpr int oMSK  = 8616;     // 2*8 (int)
static constexpr int oIDX  = 8632;     // 1 (int)
static constexpr int oIDXB = 8636;     // 512 floats = 2048 B char
static constexpr int oW1L  = 9152;     // 128*132
static constexpr int oWCL  = 26048;    // 96*132
static constexpr int kLDSFloats = 38720;
static constexpr int kDynLDS = kLDSFloats * 4;  // 154880 <= 163840
static constexpr int ROWS0 = 96;

__device__ __forceinline__ void bar_lds() {
  asm volatile("s_waitcnt lgkmcnt(0)\n\ts_barrier" ::: "memory");
}

// ---------------- Threefry-2x32 (JAX-compatible, verified R3-R10) ----------
__device__ __forceinline__ uint32_t rotl32(uint32_t x, int d) {
  return (x << d) | (x >> (32 - d));
}
__device__ __forceinline__ void tf2x32(uint32_t k0, uint32_t k1,
                                       uint32_t x0, uint32_t x1,
                                       uint32_t& o0, uint32_t& o1) {
  uint32_t ks2 = k0 ^ k1 ^ 0x1BD11BDAu;
  x0 += k0; x1 += k1;
  x0+=x1; x1=rotl32(x1,13); x1^=x0;  x0+=x1; x1=rotl32(x1,15); x1^=x0;
  x0+=x1; x1=rotl32(x1,26); x1^=x0;  x0+=x1; x1=rotl32(x1, 6); x1^=x0;
  x0+=k1; x1+=ks2+1u;
  x0+=x1; x1=rotl32(x1,17); x1^=x0;  x0+=x1; x1=rotl32(x1,29); x1^=x0;
  x0+=x1; x1=rotl32(x1,16); x1^=x0;  x0+=x1; x1=rotl32(x1,24); x1^=x0;
  x0+=ks2; x1+=k0+2u;
  x0+=x1; x1=rotl32(x1,13); x1^=x0;  x0+=x1; x1=rotl32(x1,15); x1^=x0;
  x0+=x1; x1=rotl32(x1,26); x1^=x0;  x0+=x1; x1=rotl32(x1, 6); x1^=x0;
  x0+=k0; x1+=k1+3u;
  x0+=x1; x1=rotl32(x1,17); x1^=x0;  x0+=x1; x1=rotl32(x1,29); x1^=x0;
  x0+=x1; x1=rotl32(x1,16); x1^=x0;  x0+=x1; x1=rotl32(x1,24); x1^=x0;
  x0+=k1; x1+=ks2+4u;
  x0+=x1; x1=rotl32(x1,13); x1^=x0;  x0+=x1; x1=rotl32(x1,15); x1^=x0;
  x0+=x1; x1=rotl32(x1,26); x1^=x0;  x0+=x1; x1=rotl32(x1, 6); x1^=x0;
  x0+=ks2; x1+=k0+5u;
  o0 = x0; o1 = x1;
}

__device__ __forceinline__ float sigm(float x) { return 1.0f / (1.0f + expf(-x)); }

// ---------------- prep: Whc = Wih[:,128:]+Whh; Wcomb/cbias (P1|G1 fused) ---
__global__ void prep_kernel(const float* __restrict__ Wp1,
                            const float* __restrict__ bp1,
                            const float* __restrict__ Wih,
                            const float* __restrict__ Whh,
                            const float* __restrict__ bih,
                            const float* __restrict__ bhh,
                            float* __restrict__ Whc,
                            float* __restrict__ Wcomb,
                            float* __restrict__ cbias) {
  int tid = blockIdx.x * blockDim.x + threadIdx.x;
  int nt  = gridDim.x * blockDim.x;
  for (int p = tid; p < 512 * 128; p += nt) {
    int g = p >> 7, e = p & 127;
    Whc[p] = Wih[g * 256 + 128 + e] + Whh[p];
  }
  for (int p = tid; p < 640 * 128; p += nt) {
    int n = p >> 7, e = p & 127;
    Wcomb[p] = (n < 128) ? Wp1[n * 256 + e] : Wih[(n - 128) * 256 + e];
  }
  for (int n = tid; n < 640; n += nt)
    cbias[n] = (n < 128) ? bp1[n] : (bih[n - 128] + bhh[n - 128]);
}

// ---------------- precompute gumbel perturbations pg[j][b*6+k] -------------
__global__ void gumbel_kernel(float* __restrict__ pg) {
  int idx = blockIdx.x * blockDim.x + threadIdx.x;
  if (idx >= NSTP * 192) return;
  int j = idx / 192, r = idx % 192;
  uint32_t a0, a1, y0, y1;
  tf2x32(0u, 42u, 0u, (uint32_t)j, a0, a1);
  tf2x32(a0, a1, 0u, (uint32_t)r, y0, y1);
  uint32_t bits = y0 ^ y1;
  float f = __uint_as_float((bits >> 9) | 0x3f800000u) - 1.0f;
  float u = fmaxf(f, 1.17549435e-38f);
  double g = -log(-log((double)u));
  pg[idx] = (float)g;
}

// ---------------- fp32 GEMM (unchanged) ------------------------------------
#define TM 128
#define TN 128
#define TKK 8
template <int MODE>
__global__ __launch_bounds__(256) void gemm_kernel(
    const float* __restrict__ A, const float* __restrict__ Bm, int ldb,
    const float* __restrict__ bias, float* __restrict__ C, int ldc,
    int M, int K, int relu, int NS, int c0) {
  int m0 = blockIdx.x * TM;
  int n0 = blockIdx.y * TN;
  int tid = threadIdx.x;
  __shared__ float As[TKK][TM + 4];
  __shared__ float Bs[TKK][TN + 4];

  int srow = tid >> 1;
  int skq  = (tid & 1) * 4;
  int gm   = m0 + srow;
  bool mvalid = gm < M;
  const float* Arow;
  if (MODE == 1) {
    int gmc = mvalid ? gm : 0;
    int bb = gmc / NS, cs = gmc % NS;
    Arow = A + (size_t)(bb * (LQ + 2) + c0 + cs + 2) * EE;
  } else {
    Arow = A + (size_t)gm * K;
  }
  const float* Brow = Bm + (size_t)(n0 + srow) * ldb;

  float acc[8][8] = {};
  int tm = (tid >> 4) * 8;
  int tn = (tid & 15) * 8;

  for (int k0 = 0; k0 < K; k0 += TKK) {
    float4 av = mvalid ? *(const float4*)(Arow + k0 + skq)
                       : make_float4(0.f, 0.f, 0.f, 0.f);
    float4 bv = *(const float4*)(Brow + k0 + skq);
    __syncthreads();
    As[skq + 0][srow] = av.x; As[skq + 1][srow] = av.y;
    As[skq + 2][srow] = av.z; As[skq + 3][srow] = av.w;
    Bs[skq + 0][srow] = bv.x; Bs[skq + 1][srow] = bv.y;
    Bs[skq + 2][srow] = bv.z; Bs[skq + 3][srow] = bv.w;
    __syncthreads();
#pragma unroll
    for (int kk = 0; kk < TKK; kk++) {
      float4 a0 = *(const float4*)&As[kk][tm];
      float4 a1 = *(const float4*)&As[kk][tm + 4];
      float4 b0 = *(const float4*)&Bs[kk][tn];
      float4 b1 = *(const float4*)&Bs[kk][tn + 4];
      float aa[8] = {a0.x, a0.y, a0.z, a0.w, a1.x, a1.y, a1.z, a1.w};
      float bb2[8] = {b0.x, b0.y, b0.z, b0.w, b1.x, b1.y, b1.z, b1.w};
#pragma unroll
      for (int i = 0; i < 8; i++)
#pragma unroll
        for (int jx = 0; jx < 8; jx++) acc[i][jx] += aa[i] * bb2[jx];
    }
  }
#pragma unroll
  for (int i = 0; i < 8; i++) {
    int gm2 = m0 + tm + i;
    if (gm2 >= M) break;
#pragma unroll
    for (int jx = 0; jx < 8; jx++) {
      int gn = n0 + tn + jx;
      float v = acc[i][jx] + bias[gn];
      if (relu) v = fmaxf(v, 0.f);
      C[(size_t)gm2 * ldc + gn] = v;
    }
  }
}

// ---------------- scan9: R5 schedule + weights partially in big LDS --------
__global__ __launch_bounds__(512) void scan9_kernel(
    const float* __restrict__ exf, const float* __restrict__ pg,
    const int* __restrict__ mask, const int* __restrict__ length,
    const float* __restrict__ Wp1, const float* __restrict__ Wp2,
    const float* __restrict__ bp2, const float* __restrict__ Whc,
    float* __restrict__ state, float* __restrict__ out,
    int c0, int NS, int init) {
  extern __shared__ float lds[];
  const int b = blockIdx.x;
  const int tid = threadIdx.x;
  const int q = tid & 3;        // h-quarter for dots
  const int gb = tid >> 2;      // 0..127

  float* h_pad = lds + oHP;
  float* hh_s  = lds + oHH;
  float* ghh_s = lds + oGHH;
  float* scv   = lds + oSCV;
  float* wp2_l = lds + oWP2;
  float* gum_l = lds + oGUM;
  int*   msk_l = (int*)(lds + oMSK);
  int*   idx_s = (int*)(lds + oIDX);
  char*  idxb  = (char*)(lds + oIDXB);
  float* wp1L  = lds + oW1L;   // [128][132]
  float* whcL  = lds + oWCL;   // [96][132]

  const float bp2v = bp2[0];
  const int len_b = length[b];

  // ---- one-time LDS preload of weights (amortized over NS steps)
  for (int p = tid; p < 128 * 128; p += 512) {
    int r = p >> 7, cx = p & 127;
    wp1L[r * 132 + cx] = Wp1[r * 256 + 128 + cx];
  }
  for (int p = tid; p < ROWS0 * 128; p += 512) {
    int r = p >> 7, cx = p & 127;
    whcL[r * 132 + cx] = Whc[r * 128 + cx];
  }

  float c_r = 0.f, lp_r = 0.f;
  if (tid < 144) h_pad[tid] = 0.f;
  if (tid < 128) {
    if (!init) h_pad[(tid >> 5) * 36 + (tid & 31)] = state[b * 128 + tid];
    c_r = init ? 0.f : state[4096 + b * 128 + tid];
    wp2_l[tid] = Wp2[tid];
  }
  if (tid == 0) lp_r = init ? 0.f : state[8192 + b];

  // ---- prologue: stage step 0; prefetch step 1 into regs
  float4 pf0, pf1, pf2;
  float pfg = 0.f; int pfm = 0;
  {
    const float4* e0 = (const float4*)(exf + (size_t)b * NS * 3840);
    ((float4*)(lds + oEXF))[tid] = e0[tid];
    if (tid < 448) ((float4*)(lds + oEXF))[512 + tid] = e0[512 + tid];
    if (tid < 6) {
      gum_l[tid] = pg[(size_t)c0 * 192 + b * 6 + tid];
      msk_l[tid] = mask[((size_t)b * LQ + c0 + 1) * 6 + tid];
    }
    int cs1 = (NS > 1) ? 1 : 0;
    const float4* e1 = (const float4*)(exf + ((size_t)b * NS + cs1) * 3840);
    if (tid >= 64) {
      int i0 = tid - 64;
      pf0 = e1[i0];
      pf1 = e1[448 + i0];
      if (tid < 128) pf2 = e1[896 + i0];
    }
    if (tid >= 384 && tid < 390)
      pfg = pg[(size_t)(c0 + cs1) * 192 + b * 6 + (tid - 384)];
    if (tid >= 390 && tid < 396)
      pfm = mask[((size_t)b * LQ + c0 + cs1 + 1) * 6 + (tid - 390)];
  }
  bar_lds();

  for (int cs = 0; cs < NS; ++cs) {
    const int buf = cs & 1;
    const int nb = buf ^ 1;
    float* EXFb = lds + oEXF + buf * 3840;
    float* EXFn = lds + oEXF + nb * 3840;

    // ---- phase A: h once; hid_h (LDS W) + 4 gate-h partials (LDS/L2 W)
    {
      const float4* hp4 = (const float4*)(h_pad + q * 36);
      float4 hv[8];
#pragma unroll
      for (int i = 0; i < 8; i++) hv[i] = hp4[i];

      float hidp = 0.f, p0 = 0.f, p1 = 0.f, p2 = 0.f, p3 = 0.f;
      {
        const float4* w4 = (const float4*)(wp1L + (size_t)gb * 132 + q * 32);
#pragma unroll
        for (int i = 0; i < 8; i++) {
          float4 w = w4[i];
          hidp += w.x * hv[i].x + w.y * hv[i].y + w.z * hv[i].z + w.w * hv[i].w;
        }
      }
      if (gb < ROWS0) {  // wave-uniform (waves 0-5 vs 6-7)
        const float4* a4 = (const float4*)(whcL + (size_t)gb * 132 + q * 32);
#pragma unroll
        for (int i = 0; i < 8; i++) {
          float4 a = a4[i];
          p0 += a.x * hv[i].x + a.y * hv[i].y + a.z * hv[i].z + a.w * hv[i].w;
        }
      } else {
        const float4* a4 = (const float4*)(Whc + (size_t)gb * 128 + q * 32);
#pragma unroll
        for (int i = 0; i < 8; i++) {
          float4 a = a4[i];
          p0 += a.x * hv[i].x + a.y * hv[i].y + a.z * hv[i].z + a.w * hv[i].w;
        }
      }
      {
        const float4* a1p = (const float4*)(Whc + ((size_t)gb + 128) * 128 + q * 32);
        const float4* a2p = (const float4*)(Whc + ((size_t)gb + 256) * 128 + q * 32);
        const float4* a3p = (const float4*)(Whc + ((size_t)gb + 384) * 128 + q * 32);
#pragma unroll
        for (int i = 0; i < 8; i++) {
          float4 a = a1p[i];
          p1 += a.x * hv[i].x + a.y * hv[i].y + a.z * hv[i].z + a.w * hv[i].w;
          a = a2p[i];
          p2 += a.x * hv[i].x + a.y * hv[i].y + a.z * hv[i].z + a.w * hv[i].w;
          a = a3p[i];
          p3 += a.x * hv[i].x + a.y * hv[i].y + a.z * hv[i].z + a.w * hv[i].w;
        }
      }
      hidp += __shfl_xor(hidp, 1); hidp += __shfl_xor(hidp, 2);
      p0 += __shfl_xor(p0, 1); p0 += __shfl_xor(p0, 2);
      p1 += __shfl_xor(p1, 1); p1 += __shfl_xor(p1, 2);
      p2 += __shfl_xor(p2, 1); p2 += __shfl_xor(p2, 2);
      p3 += __shfl_xor(p3, 1); p3 += __shfl_xor(p3, 2);
      if (q == 0) {
        hh_s[gb] = hidp;
        ghh_s[gb] = p0; ghh_s[128 + gb] = p1;
        ghh_s[256 + gb] = p2; ghh_s[384 + gb] = p3;
      }
    }
    bar_lds();

    // ---- phase BC: wave 0 scores+samples; waves 1-7 park & prefetch
    if (tid < 64) {
      const int k = tid >> 3, r = tid & 7;
      float s = 0.f;
      if (k < 6) {
        const float* pb = &EXFb[k * 640 + r * 16];
        const float* hb = &hh_s[r * 16];
        const float* wb = &wp2_l[r * 16];
#pragma unroll
        for (int ii = 0; ii < 4; ii++) {
          float4 p = *(const float4*)(pb + ii * 4);
          float4 hh = *(const float4*)(hb + ii * 4);
          float4 w = *(const float4*)(wb + ii * 4);
          s += fmaxf(p.x + hh.x, 0.f) * w.x + fmaxf(p.y + hh.y, 0.f) * w.y +
               fmaxf(p.z + hh.z, 0.f) * w.z + fmaxf(p.w + hh.w, 0.f) * w.w;
        }
      }
      s += __shfl_xor(s, 1);
      s += __shfl_xor(s, 2);
      s += __shfl_xor(s, 4);
      if (k < 6 && r == 0) scv[k] = fmaxf(s + bp2v, 0.f);
      asm volatile("s_waitcnt lgkmcnt(0)" ::: "memory");
      if (tid == 0) {
        float best = -3.4e38f, mx = -1e9f, libest = -1e9f, ssum;
        int bi = 0;
        float lgv[6];
#pragma unroll
        for (int k2 = 0; k2 < 6; k2++) {
          float lg = msk_l[buf * 8 + k2] ? scv[k2] : -1e9f;
          float pt = gum_l[buf * 8 + k2] + lg;
          if (pt > best) { best = pt; bi = k2; libest = lg; }
          mx = fmaxf(mx, lg);
          lgv[k2] = lg;
        }
        ssum = 0.f;
#pragma unroll
        for (int k2 = 0; k2 < 6; k2++) ssum += __expf(lgv[k2] - mx);
        float logp = libest - mx - __logf(ssum);
        if (len_b > c0 + cs + 1) lp_r += logp;
        *idx_s = bi;
        idxb[cs] = (char)bi;
      }
    } else {
      int i0 = tid - 64;
      ((float4*)EXFn)[i0] = pf0;
      ((float4*)EXFn)[448 + i0] = pf1;
      if (tid < 128) ((float4*)EXFn)[896 + i0] = pf2;
      if (tid >= 384 && tid < 390) gum_l[nb * 8 + tid - 384] = pfg;
      if (tid >= 390 && tid < 396) msk_l[nb * 8 + tid - 390] = pfm;
      int csp = (cs + 2 < NS) ? cs + 2 : NS - 1;
      const float4* en = (const float4*)(exf + ((size_t)b * NS + csp) * 3840);
      pf0 = en[i0];
      pf1 = en[448 + i0];
      if (tid < 128) pf2 = en[896 + i0];
      if (tid >= 384 && tid < 390)
        pfg = pg[(size_t)(c0 + csp) * 192 + b * 6 + (tid - 384)];
      if (tid >= 390 && tid < 396)
        pfm = mask[((size_t)b * LQ + c0 + csp + 1) * 6 + (tid - 390)];
    }
    bar_lds();

    // ---- phase D: LSTM pointwise (tid<128)
    if (tid < 128) {
      int base = *idx_s * 640 + 128 + tid;
      float iv = EXFb[base] + ghh_s[tid];
      float fv = EXFb[base + 128] + ghh_s[128 + tid];
      float gg = EXFb[base + 256] + ghh_s[256 + tid];
      float ov = EXFb[base + 384] + ghh_s[384 + tid];
      float c2 = sigm(fv) * c_r + sigm(iv) * tanhf(gg);
      float h2 = sigm(ov) * tanhf(c2);
      c_r = c2;
      h_pad[(tid >> 5) * 36 + (tid & 31)] = h2;
    }
    bar_lds();
  }

  // ---- epilogue
  if (tid < 128) {
    state[b * 128 + tid] = h_pad[(tid >> 5) * 36 + (tid & 31)];
    state[4096 + b * 128 + tid] = c_r;
  }
  if (tid == 0) {
    state[8192 + b] = lp_r;
    out[b] = lp_r;
  }
  for (int i = tid; i < NS; i += 512)
    out[32 + (size_t)(c0 + i) * 32 + b] = (float)idxb[i];
}

// ---------------- scan5 fallback (R7, verified 901us/chunk) ----------------
__global__ __launch_bounds__(512, 2) void scan5_kernel(
    const float* __restrict__ exf, const float* __restrict__ pg,
    const int* __restrict__ mask, const int* __restrict__ length,
    const float* __restrict__ Wp1, const float* __restrict__ Wp2,
    const float* __restrict__ bp2, const float* __restrict__ Whc,
    float* __restrict__ state, float* __restrict__ out,
    int c0, int NS, int init) {
  const int b = blockIdx.x;
  const int tid = threadIdx.x;
  const int q = tid & 3;
  const int gb = tid >> 2;

  __shared__ float EXF[2][3840];
  __shared__ float h_pad[144];
  __shared__ float hh_s[128];
  __shared__ float ghh_s[512];
  __shared__ float scv[8];
  __shared__ float wp2_lds[128];
  __shared__ float gum_lds[2][8];
  __shared__ int   msk_lds[2][8];
  __shared__ int   idx_s;
  __shared__ char  idxb[2048];

  const float bp2v = bp2[0];
  const int len_b = length[b];

  float c_r = 0.f, lp_r = 0.f;
  if (tid < 144) h_pad[tid] = 0.f;
  if (tid < 128) {
    if (!init) h_pad[(tid >> 5) * 36 + (tid & 31)] = state[b * 128 + tid];
    c_r = init ? 0.f : state[4096 + b * 128 + tid];
    wp2_lds[tid] = Wp2[tid];
  }
  if (tid == 0) lp_r = init ? 0.f : state[8192 + b];

  float4 pf0, pf1, pf2;
  float pfg = 0.f; int pfm = 0;
  {
    const float4* e0 = (const float4*)(exf + (size_t)b * NS * 3840);
    ((float4*)EXF[0])[tid] = e0[tid];
    if (tid < 448) ((float4*)EXF[0])[512 + tid] = e0[512 + tid];
    if (tid < 6) {
      gum_lds[0][tid] = pg[(size_t)c0 * 192 + b * 6 + tid];
      msk_lds[0][tid] = mask[((size_t)b * LQ + c0 + 1) * 6 + tid];
    }
    int cs1 = (NS > 1) ? 1 : 0;
    const float4* e1 = (const float4*)(exf + ((size_t)b * NS + cs1) * 3840);
    if (tid >= 64) {
      int i0 = tid - 64;
      pf0 = e1[i0];
      pf1 = e1[448 + i0];
      if (tid < 128) pf2 = e1[896 + i0];
    }
    if (tid >= 384 && tid < 390)
      pfg = pg[(size_t)(c0 + cs1) * 192 + b * 6 + (tid - 384)];
    if (tid >= 390 && tid < 396)
      pfm = mask[((size_t)b * LQ + c0 + cs1 + 1) * 6 + (tid - 390)];
  }
  bar_lds();

  for (int cs = 0; cs < NS; ++cs) {
    const int buf = cs & 1;
    const int nb = buf ^ 1;

    {
      const float4* hp4 = (const float4*)(h_pad + q * 36);
      const float4* s0 = (const float4*)(Wp1 + (size_t)gb * 256 + 128 + q * 32);
      const float4* a0 = (const float4*)(Whc + ((size_t)gb + 0) * 128 + q * 32);
      const float4* a1 = (const float4*)(Whc + ((size_t)gb + 128) * 128 + q * 32);
      const float4* a2 = (const float4*)(Whc + ((size_t)gb + 256) * 128 + q * 32);
      const float4* a3 = (const float4*)(Whc + ((size_t)gb + 384) * 128 + q * 32);
      float hidp = 0.f, p0 = 0.f, p1 = 0.f, p2 = 0.f, p3 = 0.f;
#pragma unroll
      for (int i = 0; i < 8; i++) {
        float4 hv = hp4[i];
        float4 w = s0[i];
        hidp += w.x * hv.x + w.y * hv.y + w.z * hv.z + w.w * hv.w;
        float4 a = a0[i];
        p0 += a.x * hv.x + a.y * hv.y + a.z * hv.z + a.w * hv.w;
        a = a1[i];
        p1 += a.x * hv.x + a.y * hv.y + a.z * hv.z + a.w * hv.w;
        a = a2[i];
        p2 += a.x * hv.x + a.y * hv.y + a.z * hv.z + a.w * hv.w;
        a = a3[i];
        p3 += a.x * hv.x + a.y * hv.y + a.z * hv.z + a.w * hv.w;
      }
      hidp += __shfl_xor(hidp, 1); hidp += __shfl_xor(hidp, 2);
      p0 += __shfl_xor(p0, 1); p0 += __shfl_xor(p0, 2);
      p1 += __shfl_xor(p1, 1); p1 += __shfl_xor(p1, 2);
      p2 += __shfl_xor(p2, 1); p2 += __shfl_xor(p2, 2);
      p3 += __shfl_xor(p3, 1); p3 += __shfl_xor(p3, 2);
      if (q == 0) {
        hh_s[gb] = hidp;
        ghh_s[gb] = p0; ghh_s[128 + gb] = p1;
        ghh_s[256 + gb] = p2; ghh_s[384 + gb] = p3;
      }
    }
    bar_lds();

    if (tid < 64) {
      const int k = tid >> 3, r = tid & 7;
      float s = 0.f;
      if (k < 6) {
        const float* pb = &EXF[buf][k * 640 + r * 16];
        const float* hb = &hh_s[r * 16];
        const float* wb = &wp2_lds[r * 16];
#pragma unroll
        for (int ii = 0; ii < 4; ii++) {
          float4 p = *(const float4*)(pb + ii * 4);
          float4 hh = *(const float4*)(hb + ii * 4);
          float4 w = *(const float4*)(wb + ii * 4);
          s += fmaxf(p.x + hh.x, 0.f) * w.x + fmaxf(p.y + hh.y, 0.f) * w.y +
               fmaxf(p.z + hh.z, 0.f) * w.z + fmaxf(p.w + hh.w, 0.f) * w.w;
        }
      }
      s += __shfl_xor(s, 1);
      s += __shfl_xor(s, 2);
      s += __shfl_xor(s, 4);
      if (k < 6 && r == 0) scv[k] = fmaxf(s + bp2v, 0.f);
      asm volatile("s_waitcnt lgkmcnt(0)" ::: "memory");
      if (tid == 0) {
        float best = -3.4e38f, mx = -1e9f, libest = -1e9f, ssum;
        int bi = 0;
        float lgv[6];
#pragma unroll
        for (int k2 = 0; k2 < 6; k2++) {
          float lg = msk_lds[buf][k2] ? scv[k2] : -1e9f;
          float pt = gum_lds[buf][k2] + lg;
          if (pt > best) { best = pt; bi = k2; libest = lg; }
          mx = fmaxf(mx, lg);
          lgv[k2] = lg;
        }
        ssum = 0.f;
#pragma unroll
        for (int k2 = 0; k2 < 6; k2++) ssum += __expf(lgv[k2] - mx);
        float logp = libest - mx - __logf(ssum);
        if (len_b > c0 + cs + 1) lp_r += logp;
        idx_s = bi;
        idxb[cs] = (char)bi;
      }
    } else {
      int i0 = tid - 64;
      ((float4*)EXF[nb])[i0] = pf0;
      ((float4*)EXF[nb])[448 + i0] = pf1;
      if (tid < 128) ((float4*)EXF[nb])[896 + i0] = pf2;
      if (tid >= 384 && tid < 390) gum_lds[nb][tid - 384] = pfg;
      if (tid >= 390 && tid < 396) msk_lds[nb][tid - 390] = pfm;
      int csp = (cs + 2 < NS) ? cs + 2 : NS - 1;
      const float4* en = (const float4*)(exf + ((size_t)b * NS + csp) * 3840);
      pf0 = en[i0];
      pf1 = en[448 + i0];
      if (tid < 128) pf2 = en[896 + i0];
      if (tid >= 384 && tid < 390)
        pfg = pg[(size_t)(c0 + csp) * 192 + b * 6 + (tid - 384)];
      if (tid >= 390 && tid < 396)
        pfm = mask[((size_t)b * LQ + c0 + csp + 1) * 6 + (tid - 390)];
    }
    bar_lds();

    if (tid < 128) {
      int base = idx_s * 640 + 128 + tid;
      float iv = EXF[buf][base] + ghh_s[tid];
      float fv = EXF[buf][base + 128] + ghh_s[128 + tid];
      float gg = EXF[buf][base + 256] + ghh_s[256 + tid];
      float ov = EXF[buf][base + 384] + ghh_s[384 + tid];
      float c2 = sigm(fv) * c_r + sigm(iv) * tanhf(gg);
      float h2 = sigm(ov) * tanhf(c2);
      c_r = c2;
      h_pad[(tid >> 5) * 36 + (tid & 31)] = h2;
    }
    bar_lds();
  }

  if (tid < 128) {
    state[b * 128 + tid] = h_pad[(tid >> 5) * 36 + (tid & 31)];
    state[4096 + b * 128 + tid] = c_r;
  }
  if (tid == 0) {
    state[8192 + b] = lp_r;
    out[b] = lp_r;
  }
  for (int i = tid; i < NS; i += 512)
    out[32 + (size_t)(c0 + i) * 32 + b] = (float)idxb[i];
}

__global__ void sentinel_kernel(float* out, int n, float val) {
  int i = blockIdx.x * blockDim.x + threadIdx.x;
  if (i < n) out[i] = val;
}

// ---------------------------------------------------------------------------
extern "C" void kernel_launch(void* const* d_in, const int* in_sizes, int n_in,
                              void* d_out, int out_size, void* d_ws,
                              size_t ws_size, hipStream_t stream) {
  const float* memory = (const float*)d_in[0];
  const int* mask = (const int*)d_in[1];     // bool delivered as int32
  const int* length = (const int*)d_in[2];
  const float* W1  = (const float*)d_in[3];
  const float* b1  = (const float*)d_in[4];
  const float* Wp1 = (const float*)d_in[5];
  const float* bp1 = (const float*)d_in[6];
  const float* Wp2 = (const float*)d_in[7];
  const float* bp2 = (const float*)d_in[8];
  const float* Wih = (const float*)d_in[9];
  const float* Whh = (const float*)d_in[10];
  const float* bih = (const float*)d_in[11];
  const float* bhh = (const float*)d_in[12];
  float* out = (float*)d_out;

  char* ws = (char*)d_ws;
  const size_t o_whc   = 0;                    // 512*128*4  = 262144
  const size_t o_wcomb = 262144;               // 640*128*4  = 327680
  const size_t o_cbias = 589824;               // 640*4      = 2560
  const size_t o_state = 592384;               // -> pad 36864
  const size_t o_pg    = 629248;               // 2047*192*4 = 1572096
  const size_t o_buf   = 2201344;              // chunk buffers

  const size_t per_cs = 32ull * (768 + 3840) * 4;  // 589824
  long long usable = (long long)ws_size - (long long)o_buf;
  int CS = (usable > 0) ? (int)(usable / (long long)per_cs) : 0;
  if (CS > NSTP) CS = NSTP;
  if (CS < 1) {
    float val = -100000.0f - (float)(ws_size >> 20);
    sentinel_kernel<<<(out_size + 255) / 256, 256, 0, stream>>>(out, out_size, val);
    return;
  }

  float* Whc   = (float*)(ws + o_whc);
  float* Wcomb = (float*)(ws + o_wcomb);
  float* cbias = (float*)(ws + o_cbias);
  float* state = (float*)(ws + o_state);
  float* pgbuf = (float*)(ws + o_pg);

  // big-LDS availability (one host-side attribute call; deterministic)
  bool bigLds =
      (hipFuncSetAttribute((const void*)scan9_kernel,
                           hipFuncAttributeMaxDynamicSharedMemorySize,
                           kDynLDS) == hipSuccess);

  prep_kernel<<<64, 256, 0, stream>>>(Wp1, bp1, Wih, Whh, bih, bhh,
                                      Whc, Wcomb, cbias);
  gumbel_kernel<<<(NSTP * 192 + 255) / 256, 256, 0, stream>>>(pgbuf);

  int nchunks = (NSTP + CS - 1) / CS;
  for (int c = 0; c < nchunks; ++c) {
    int c0 = c * CS;
    int NS = (c0 + CS <= NSTP) ? CS : (NSTP - c0);
    int Mcf = 32 * NS;
    int M6  = Mcf * 6;

    float* cf  = (float*)(ws + o_buf);
    float* exf = cf + (size_t)Mcf * 768;

    gemm_kernel<1><<<dim3((Mcf + TM - 1) / TM, 768 / TN), 256, 0, stream>>>(
        memory, W1, 256, b1, cf, 768, Mcf, 256, 1, NS, c0);
    gemm_kernel<0><<<dim3((M6 + TM - 1) / TM, 640 / TN), 256, 0, stream>>>(
        cf, Wcomb, 128, cbias, exf, 640, M6, 128, 0, NS, c0);
    if (bigLds) {
      scan9_kernel<<<BB, 512, kDynLDS, stream>>>(
          exf, pgbuf, mask, length, Wp1, Wp2, bp2, Whc, state, out, c0, NS,
          (c == 0) ? 1 : 0);
    } else {
      scan5_kernel<<<BB, 512, 0, stream>>>(
          exf, pgbuf, mask, length, Wp1, Wp2, bp2, Whc, state, out, c0, NS,
          (c == 0) ? 1 : 0);
    }
  }
}

// Round 12
// 4281.250 us; speedup vs baseline: 4.1922x; 1.5853x over previous
//
#include <hip/hip_runtime.h>
#include <hip/hip_bf16.h>
#include <cstdint>

// ---------------------------------------------------------------------------
// B=32, L=2048, E=256, H=128, C=128. Scan steps j=0..2046 (t=j+1).
// R12: revert scan to byte-exact scan5 (R5/R7 verified 906us/chunk; R6-R11's
// six scan-internal restructures ALL regressed). New lever: fuse GEMMs into
// the scan launch. pipe_kernel(c): blocks 0-31 = scan(c); next = GEMM2
// (exf for c+1 from cf[c+1] made last launch); rest = GEMM1 (cf for c+2).
// 2-deep pipeline, double-buffered cf/exf, kernel-boundary ordering only.
// GEMM roles: tid<256 predicated work, uniform barriers.
// ---------------------------------------------------------------------------
static constexpr int BB   = 32;
static constexpr int LQ   = 2048;
static constexpr int NSTP = 2047;
static constexpr int EE   = 256;

// scan LDS byte offsets within the 35KB union
static constexpr int bEXF  = 0;        // 2*3840*4 = 30720
static constexpr int bHP   = 30720;    // 144*4
static constexpr int bHH   = 31296;    // 128*4
static constexpr int bGHH  = 31808;    // 512*4
static constexpr int bSCV  = 33856;    // 8*4
static constexpr int bWP2  = 33888;    // 128*4
static constexpr int bGUM  = 34400;    // 16*4
static constexpr int bMSK  = 34464;    // 16*4
static constexpr int bIDX  = 34528;    // 16
static constexpr int bIDXB = 34544;    // 448
static constexpr int kSmem = 35008;
static constexpr int CSMAX = 448;      // idxb capacity

__device__ __forceinline__ void bar_lds() {
  asm volatile("s_waitcnt lgkmcnt(0)\n\ts_barrier" ::: "memory");
}

// ---------------- Threefry-2x32 (JAX-compatible, verified R3-R11) ----------
__device__ __forceinline__ uint32_t rotl32(uint32_t x, int d) {
  return (x << d) | (x >> (32 - d));
}
__device__ __forceinline__ void tf2x32(uint32_t k0, uint32_t k1,
                                       uint32_t x0, uint32_t x1,
                                       uint32_t& o0, uint32_t& o1) {
  uint32_t ks2 = k0 ^ k1 ^ 0x1BD11BDAu;
  x0 += k0; x1 += k1;
  x0+=x1; x1=rotl32(x1,13); x1^=x0;  x0+=x1; x1=rotl32(x1,15); x1^=x0;
  x0+=x1; x1=rotl32(x1,26); x1^=x0;  x0+=x1; x1=rotl32(x1, 6); x1^=x0;
  x0+=k1; x1+=ks2+1u;
  x0+=x1; x1=rotl32(x1,17); x1^=x0;  x0+=x1; x1=rotl32(x1,29); x1^=x0;
  x0+=x1; x1=rotl32(x1,16); x1^=x0;  x0+=x1; x1=rotl32(x1,24); x1^=x0;
  x0+=ks2; x1+=k0+2u;
  x0+=x1; x1=rotl32(x1,13); x1^=x0;  x0+=x1; x1=rotl32(x1,15); x1^=x0;
  x0+=x1; x1=rotl32(x1,26); x1^=x0;  x0+=x1; x1=rotl32(x1, 6); x1^=x0;
  x0+=k0; x1+=k1+3u;
  x0+=x1; x1=rotl32(x1,17); x1^=x0;  x0+=x1; x1=rotl32(x1,29); x1^=x0;
  x0+=x1; x1=rotl32(x1,16); x1^=x0;  x0+=x1; x1=rotl32(x1,24); x1^=x0;
  x0+=k1; x1+=ks2+4u;
  x0+=x1; x1=rotl32(x1,13); x1^=x0;  x0+=x1; x1=rotl32(x1,15); x1^=x0;
  x0+=x1; x1=rotl32(x1,26); x1^=x0;  x0+=x1; x1=rotl32(x1, 6); x1^=x0;
  x0+=ks2; x1+=k0+5u;
  o0 = x0; o1 = x1;
}

__device__ __forceinline__ float sigm(float x) { return 1.0f / (1.0f + expf(-x)); }

// ---------------- prep: Whc = Wih[:,128:]+Whh; Wcomb/cbias -----------------
__global__ void prep_kernel(const float* __restrict__ Wp1,
                            const float* __restrict__ bp1,
                            const float* __restrict__ Wih,
                            const float* __restrict__ Whh,
                            const float* __restrict__ bih,
                            const float* __restrict__ bhh,
                            float* __restrict__ Whc,
                            float* __restrict__ Wcomb,
                            float* __restrict__ cbias) {
  int tid = blockIdx.x * blockDim.x + threadIdx.x;
  int nt  = gridDim.x * blockDim.x;
  for (int p = tid; p < 512 * 128; p += nt) {
    int g = p >> 7, e = p & 127;
    Whc[p] = Wih[g * 256 + 128 + e] + Whh[p];
  }
  for (int p = tid; p < 640 * 128; p += nt) {
    int n = p >> 7, e = p & 127;
    Wcomb[p] = (n < 128) ? Wp1[n * 256 + e] : Wih[(n - 128) * 256 + e];
  }
  for (int n = tid; n < 640; n += nt)
    cbias[n] = (n < 128) ? bp1[n] : (bih[n - 128] + bhh[n - 128]);
}

// ---------------- precompute gumbel perturbations pg[j][b*6+k] -------------
__global__ void gumbel_kernel(float* __restrict__ pg) {
  int idx = blockIdx.x * blockDim.x + threadIdx.x;
  if (idx >= NSTP * 192) return;
  int j = idx / 192, r = idx % 192;
  uint32_t a0, a1, y0, y1;
  tf2x32(0u, 42u, 0u, (uint32_t)j, a0, a1);
  tf2x32(a0, a1, 0u, (uint32_t)r, y0, y1);
  uint32_t bits = y0 ^ y1;
  float f = __uint_as_float((bits >> 9) | 0x3f800000u) - 1.0f;
  float u = fmaxf(f, 1.17549435e-38f);
  double g = -log(-log((double)u));
  pg[idx] = (float)g;
}

// ---------------- GEMM body (shared by standalone + fused) -----------------
#define TM 128
#define TN 128
#define TKK 8
// smem layout: As [8][132] floats, then Bs [8][132]
template <int MODE>
__device__ __forceinline__ void gemm_body(
    int bid2, int tid, float* As, float* Bs,
    const float* __restrict__ A, const float* __restrict__ Bm, int ldb,
    const float* __restrict__ bias, float* __restrict__ C, int ldc,
    int M, int K, int relu, int NS, int c0) {
  int mB = (M + TM - 1) / TM;
  int m0 = (bid2 % mB) * TM;
  int n0 = (bid2 / mB) * TN;

  int srow = tid >> 1;
  int skq  = (tid & 1) * 4;
  int gm   = m0 + srow;
  bool mvalid = (tid < 256) && (gm < M);
  const float* Arow = A;
  if (tid < 256) {
    if (MODE == 1) {
      int gmc = mvalid ? gm : 0;
      int bb = gmc / NS, cs = gmc % NS;
      Arow = A + (size_t)(bb * (LQ + 2) + c0 + cs + 2) * EE;
    } else {
      Arow = A + (size_t)(mvalid ? gm : 0) * K;
    }
  }
  const float* Brow = Bm + (size_t)(n0 + srow) * ldb;

  float acc[8][8] = {};
  int tm = (tid >> 4) * 8;
  int tn = (tid & 15) * 8;

  for (int k0 = 0; k0 < K; k0 += TKK) {
    float4 av = make_float4(0.f, 0.f, 0.f, 0.f), bv = av;
    if (tid < 256) {
      if (mvalid) av = *(const float4*)(Arow + k0 + skq);
      bv = *(const float4*)(Brow + k0 + skq);
    }
    __syncthreads();
    if (tid < 256) {
      As[(skq + 0) * 132 + srow] = av.x; As[(skq + 1) * 132 + srow] = av.y;
      As[(skq + 2) * 132 + srow] = av.z; As[(skq + 3) * 132 + srow] = av.w;
      Bs[(skq + 0) * 132 + srow] = bv.x; Bs[(skq + 1) * 132 + srow] = bv.y;
      Bs[(skq + 2) * 132 + srow] = bv.z; Bs[(skq + 3) * 132 + srow] = bv.w;
    }
    __syncthreads();
    if (tid < 256) {
#pragma unroll
      for (int kk = 0; kk < TKK; kk++) {
        float4 a0 = *(const float4*)&As[kk * 132 + tm];
        float4 a1 = *(const float4*)&As[kk * 132 + tm + 4];
        float4 b0 = *(const float4*)&Bs[kk * 132 + tn];
        float4 b1 = *(const float4*)&Bs[kk * 132 + tn + 4];
        float aa[8] = {a0.x, a0.y, a0.z, a0.w, a1.x, a1.y, a1.z, a1.w};
        float bb2[8] = {b0.x, b0.y, b0.z, b0.w, b1.x, b1.y, b1.z, b1.w};
#pragma unroll
        for (int i = 0; i < 8; i++)
#pragma unroll
          for (int jx = 0; jx < 8; jx++) acc[i][jx] += aa[i] * bb2[jx];
      }
    }
  }
  if (tid < 256) {
#pragma unroll
    for (int i = 0; i < 8; i++) {
      int gm2 = m0 + tm + i;
      if (gm2 >= M) break;
#pragma unroll
      for (int jx = 0; jx < 8; jx++) {
        int gn = n0 + tn + jx;
        float v = acc[i][jx] + bias[gn];
        if (relu) v = fmaxf(v, 0.f);
        C[(size_t)gm2 * ldc + gn] = v;
      }
    }
  }
}

// standalone GEMM (prologue fills), 256 threads
template <int MODE>
__global__ __launch_bounds__(256) void gemm_kernel(
    const float* __restrict__ A, const float* __restrict__ Bm, int ldb,
    const float* __restrict__ bias, float* __restrict__ C, int ldc,
    int M, int K, int relu, int NS, int c0) {
  __shared__ float smg[2 * 8 * 132];
  gemm_body<MODE>(blockIdx.x, threadIdx.x, smg, smg + 8 * 132,
                  A, Bm, ldb, bias, C, ldc, M, K, relu, NS, c0);
}

// ---------------- fused pipeline kernel ------------------------------------
// blocks [0,32): scan5 body, chunk c (exfS)
// blocks [32, 32+nbG2): GEMM2: exf(c+1) = cf(c+1) @ Wcomb^T + cbias
// blocks [32+nbG2, ...): GEMM1: cf(c+2) = relu(memory @ W1^T + b1)
__global__ __launch_bounds__(512, 2) void pipe_kernel(
    // scan (chunk c)
    const float* __restrict__ exfS, const float* __restrict__ pg,
    const int* __restrict__ mask, const int* __restrict__ length,
    const float* __restrict__ Wp1, const float* __restrict__ Wp2,
    const float* __restrict__ bp2, const float* __restrict__ Whc,
    float* __restrict__ state, float* __restrict__ out,
    int c0, int NS, int init,
    // gemm2 (chunk c+1)
    const float* __restrict__ cfB, float* __restrict__ exfB,
    const float* __restrict__ Wcomb, const float* __restrict__ cbias,
    int M6n, int nbG2,
    // gemm1 (chunk c+2)
    const float* __restrict__ memory, const float* __restrict__ W1,
    const float* __restrict__ b1, float* __restrict__ cfC,
    int McfN, int NS1, int c01) {
  __shared__ __align__(16) char smem[kSmem];
  const int bidx = blockIdx.x;
  const int tid = threadIdx.x;

  if (bidx >= 32) {
    float* As = (float*)smem;
    float* Bs = As + 8 * 132;
    if (bidx < 32 + nbG2) {
      gemm_body<0>(bidx - 32, tid, As, Bs, cfB, Wcomb, 128, cbias, exfB, 640,
                   M6n, 128, 0, 0, 0);
    } else {
      gemm_body<1>(bidx - 32 - nbG2, tid, As, Bs, memory, W1, 256, b1, cfC,
                   768, McfN, 256, 1, NS1, c01);
    }
    return;
  }

  // -------------------- scan5 body (byte-exact logic) --------------------
  const int b = bidx;
  const int q = tid & 3;
  const int gb = tid >> 2;

  float* EXF0  = (float*)(smem + bEXF);          // [2][3840]
  float* h_pad = (float*)(smem + bHP);
  float* hh_s  = (float*)(smem + bHH);
  float* ghh_s = (float*)(smem + bGHH);
  float* scv   = (float*)(smem + bSCV);
  float* wp2_l = (float*)(smem + bWP2);
  float* gum_l = (float*)(smem + bGUM);          // [2][8]
  int*   msk_l = (int*)(smem + bMSK);            // [2][8]
  int*   idxp  = (int*)(smem + bIDX);
  char*  idxb  = (char*)(smem + bIDXB);

  const float bp2v = bp2[0];
  const int len_b = length[b];

  float c_r = 0.f, lp_r = 0.f;
  if (tid < 144) h_pad[tid] = 0.f;
  if (tid < 128) {
    if (!init) h_pad[(tid >> 5) * 36 + (tid & 31)] = state[b * 128 + tid];
    c_r = init ? 0.f : state[4096 + b * 128 + tid];
    wp2_l[tid] = Wp2[tid];
  }
  if (tid == 0) lp_r = init ? 0.f : state[8192 + b];

  float4 pf0, pf1, pf2;
  float pfg = 0.f; int pfm = 0;
  {
    const float4* e0 = (const float4*)(exfS + (size_t)b * NS * 3840);
    ((float4*)EXF0)[tid] = e0[tid];
    if (tid < 448) ((float4*)EXF0)[512 + tid] = e0[512 + tid];
    if (tid < 6) {
      gum_l[tid] = pg[(size_t)c0 * 192 + b * 6 + tid];
      msk_l[tid] = mask[((size_t)b * LQ + c0 + 1) * 6 + tid];
    }
    int cs1 = (NS > 1) ? 1 : 0;
    const float4* e1 = (const float4*)(exfS + ((size_t)b * NS + cs1) * 3840);
    if (tid >= 64) {
      int i0 = tid - 64;
      pf0 = e1[i0];
      pf1 = e1[448 + i0];
      if (tid < 128) pf2 = e1[896 + i0];
    }
    if (tid >= 384 && tid < 390)
      pfg = pg[(size_t)(c0 + cs1) * 192 + b * 6 + (tid - 384)];
    if (tid >= 390 && tid < 396)
      pfm = mask[((size_t)b * LQ + c0 + cs1 + 1) * 6 + (tid - 390)];
  }
  bar_lds();

  for (int cs = 0; cs < NS; ++cs) {
    const int buf = cs & 1;
    const int nb = buf ^ 1;
    float* EXFb = EXF0 + buf * 3840;
    float* EXFn = EXF0 + nb * 3840;

    {
      const float4* hp4 = (const float4*)(h_pad + q * 36);
      const float4* s0 = (const float4*)(Wp1 + (size_t)gb * 256 + 128 + q * 32);
      const float4* a0 = (const float4*)(Whc + ((size_t)gb + 0) * 128 + q * 32);
      const float4* a1 = (const float4*)(Whc + ((size_t)gb + 128) * 128 + q * 32);
      const float4* a2 = (const float4*)(Whc + ((size_t)gb + 256) * 128 + q * 32);
      const float4* a3 = (const float4*)(Whc + ((size_t)gb + 384) * 128 + q * 32);
      float hidp = 0.f, p0 = 0.f, p1 = 0.f, p2 = 0.f, p3 = 0.f;
#pragma unroll
      for (int i = 0; i < 8; i++) {
        float4 hv = hp4[i];
        float4 w = s0[i];
        hidp += w.x * hv.x + w.y * hv.y + w.z * hv.z + w.w * hv.w;
        float4 a = a0[i];
        p0 += a.x * hv.x + a.y * hv.y + a.z * hv.z + a.w * hv.w;
        a = a1[i];
        p1 += a.x * hv.x + a.y * hv.y + a.z * hv.z + a.w * hv.w;
        a = a2[i];
        p2 += a.x * hv.x + a.y * hv.y + a.z * hv.z + a.w * hv.w;
        a = a3[i];
        p3 += a.x * hv.x + a.y * hv.y + a.z * hv.z + a.w * hv.w;
      }
      hidp += __shfl_xor(hidp, 1); hidp += __shfl_xor(hidp, 2);
      p0 += __shfl_xor(p0, 1); p0 += __shfl_xor(p0, 2);
      p1 += __shfl_xor(p1, 1); p1 += __shfl_xor(p1, 2);
      p2 += __shfl_xor(p2, 1); p2 += __shfl_xor(p2, 2);
      p3 += __shfl_xor(p3, 1); p3 += __shfl_xor(p3, 2);
      if (q == 0) {
        hh_s[gb] = hidp;
        ghh_s[gb] = p0; ghh_s[128 + gb] = p1;
        ghh_s[256 + gb] = p2; ghh_s[384 + gb] = p3;
      }
    }
    bar_lds();

    if (tid < 64) {
      const int k = tid >> 3, r = tid & 7;
      float s = 0.f;
      if (k < 6) {
        const float* pb = &EXFb[k * 640 + r * 16];
        const float* hb = &hh_s[r * 16];
        const float* wb = &wp2_l[r * 16];
#pragma unroll
        for (int ii = 0; ii < 4; ii++) {
          float4 p = *(const float4*)(pb + ii * 4);
          float4 hh = *(const float4*)(hb + ii * 4);
          float4 w = *(const float4*)(wb + ii * 4);
          s += fmaxf(p.x + hh.x, 0.f) * w.x + fmaxf(p.y + hh.y, 0.f) * w.y +
               fmaxf(p.z + hh.z, 0.f) * w.z + fmaxf(p.w + hh.w, 0.f) * w.w;
        }
      }
      s += __shfl_xor(s, 1);
      s += __shfl_xor(s, 2);
      s += __shfl_xor(s, 4);
      if (k < 6 && r == 0) scv[k] = fmaxf(s + bp2v, 0.f);
      asm volatile("s_waitcnt lgkmcnt(0)" ::: "memory");
      if (tid == 0) {
        float best = -3.4e38f, mx = -1e9f, libest = -1e9f, ssum;
        int bi = 0;
        float lgv[6];
#pragma unroll
        for (int k2 = 0; k2 < 6; k2++) {
          float lg = msk_l[buf * 8 + k2] ? scv[k2] : -1e9f;
          float pt = gum_l[buf * 8 + k2] + lg;
          if (pt > best) { best = pt; bi = k2; libest = lg; }
          mx = fmaxf(mx, lg);
          lgv[k2] = lg;
        }
        ssum = 0.f;
#pragma unroll
        for (int k2 = 0; k2 < 6; k2++) ssum += __expf(lgv[k2] - mx);
        float logp = libest - mx - __logf(ssum);
        if (len_b > c0 + cs + 1) lp_r += logp;
        *idxp = bi;
        idxb[cs] = (char)bi;
      }
    } else {
      int i0 = tid - 64;
      ((float4*)EXFn)[i0] = pf0;
      ((float4*)EXFn)[448 + i0] = pf1;
      if (tid < 128) ((float4*)EXFn)[896 + i0] = pf2;
      if (tid >= 384 && tid < 390) gum_l[nb * 8 + tid - 384] = pfg;
      if (tid >= 390 && tid < 396) msk_l[nb * 8 + tid - 390] = pfm;
      int csp = (cs + 2 < NS) ? cs + 2 : NS - 1;
      const float4* en = (const float4*)(exfS + ((size_t)b * NS + csp) * 3840);
      pf0 = en[i0];
      pf1 = en[448 + i0];
      if (tid < 128) pf2 = en[896 + i0];
      if (tid >= 384 && tid < 390)
        pfg = pg[(size_t)(c0 + csp) * 192 + b * 6 + (tid - 384)];
      if (tid >= 390 && tid < 396)
        pfm = mask[((size_t)b * LQ + c0 + csp + 1) * 6 + (tid - 390)];
    }
    bar_lds();

    if (tid < 128) {
      int base = *idxp * 640 + 128 + tid;
      float iv = EXFb[base] + ghh_s[tid];
      float fv = EXFb[base + 128] + ghh_s[128 + tid];
      float gg = EXFb[base + 256] + ghh_s[256 + tid];
      float ov = EXFb[base + 384] + ghh_s[384 + tid];
      float c2 = sigm(fv) * c_r + sigm(iv) * tanhf(gg);
      float h2 = sigm(ov) * tanhf(c2);
      c_r = c2;
      h_pad[(tid >> 5) * 36 + (tid & 31)] = h2;
    }
    bar_lds();
  }

  if (tid < 128) {
    state[b * 128 + tid] = h_pad[(tid >> 5) * 36 + (tid & 31)];
    state[4096 + b * 128 + tid] = c_r;
  }
  if (tid == 0) {
    state[8192 + b] = lp_r;
    out[b] = lp_r;
  }
  for (int i = tid; i < NS; i += 512)
    out[32 + (size_t)(c0 + i) * 32 + b] = (float)idxb[i];
}

__global__ void sentinel_kernel(float* out, int n, float val) {
  int i = blockIdx.x * blockDim.x + threadIdx.x;
  if (i < n) out[i] = val;
}

// ---------------------------------------------------------------------------
extern "C" void kernel_launch(void* const* d_in, const int* in_sizes, int n_in,
                              void* d_out, int out_size, void* d_ws,
                              size_t ws_size, hipStream_t stream) {
  const float* memory = (const float*)d_in[0];
  const int* mask = (const int*)d_in[1];     // bool delivered as int32
  const int* length = (const int*)d_in[2];
  const float* W1  = (const float*)d_in[3];
  const float* b1  = (const float*)d_in[4];
  const float* Wp1 = (const float*)d_in[5];
  const float* bp1 = (const float*)d_in[6];
  const float* Wp2 = (const float*)d_in[7];
  const float* bp2 = (const float*)d_in[8];
  const float* Wih = (const float*)d_in[9];
  const float* Whh = (const float*)d_in[10];
  const float* bih = (const float*)d_in[11];
  const float* bhh = (const float*)d_in[12];
  float* out = (float*)d_out;

  char* ws = (char*)d_ws;
  const size_t o_whc   = 0;                    // 262144
  const size_t o_wcomb = 262144;               // 327680
  const size_t o_cbias = 589824;               // 2560
  const size_t o_state = 592384;               // -> pad 36864
  const size_t o_pg    = 629248;               // 1572096
  const size_t o_buf   = 2201344;

  // double-buffered cf + exf: per CS-step = 2*(768 + 3840)*32*4 B
  const size_t per_cs = 2ull * 32 * (768 + 3840) * 4;  // 1179648
  long long usable = (long long)ws_size - (long long)o_buf;
  int CS = (usable > 0) ? (int)(usable / (long long)per_cs) : 0;
  if (CS > CSMAX) CS = CSMAX;
  if (CS > NSTP) CS = NSTP;
  if (CS < 1) {
    float val = -100000.0f - (float)(ws_size >> 20);
    sentinel_kernel<<<(out_size + 255) / 256, 256, 0, stream>>>(out, out_size, val);
    return;
  }

  float* Whc   = (float*)(ws + o_whc);
  float* Wcomb = (float*)(ws + o_wcomb);
  float* cbias = (float*)(ws + o_cbias);
  float* state = (float*)(ws + o_state);
  float* pgbuf = (float*)(ws + o_pg);

  const size_t cfsz = (size_t)32 * CS * 768;    // floats
  const size_t exsz = (size_t)32 * CS * 3840;   // floats
  float* cfb[2], * exfb[2];
  cfb[0]  = (float*)(ws + o_buf);
  cfb[1]  = cfb[0] + cfsz;
  exfb[0] = cfb[1] + cfsz;
  exfb[1] = exfb[0] + exsz;

  const int nc = (NSTP + CS - 1) / CS;
  auto NSof = [&](int c) { return (c * CS + CS <= NSTP) ? CS : (NSTP - c * CS); };

  prep_kernel<<<64, 256, 0, stream>>>(Wp1, bp1, Wih, Whh, bih, bhh,
                                      Whc, Wcomb, cbias);
  gumbel_kernel<<<(NSTP * 192 + 255) / 256, 256, 0, stream>>>(pgbuf);

  // prologue: cf(0), exf(0), cf(1)
  {
    int NS0 = NSof(0), Mcf0 = 32 * NS0, M60 = Mcf0 * 6;
    gemm_kernel<1><<<((Mcf0 + TM - 1) / TM) * (768 / TN), 256, 0, stream>>>(
        memory, W1, 256, b1, cfb[0], 768, Mcf0, 256, 1, NS0, 0);
    gemm_kernel<0><<<((M60 + TM - 1) / TM) * (640 / TN), 256, 0, stream>>>(
        cfb[0], Wcomb, 128, cbias, exfb[0], 640, M60, 128, 0, NS0, 0);
    if (nc > 1) {
      int NS1 = NSof(1), Mcf1 = 32 * NS1;
      gemm_kernel<1><<<((Mcf1 + TM - 1) / TM) * (768 / TN), 256, 0, stream>>>(
          memory, W1, 256, b1, cfb[1], 768, Mcf1, 256, 1, NS1, CS);
    }
  }

  for (int c = 0; c < nc; ++c) {
    int NSc = NSof(c);
    int nbG2 = 0, M6n = 0;
    if (c + 1 < nc) {
      M6n = 32 * NSof(c + 1) * 6;
      nbG2 = ((M6n + TM - 1) / TM) * (640 / TN);
    }
    int nbG1 = 0, McfN = 0, NS1 = 1, c01 = 0;
    if (c + 2 < nc) {
      NS1 = NSof(c + 2);
      McfN = 32 * NS1;
      c01 = (c + 2) * CS;
      nbG1 = ((McfN + TM - 1) / TM) * (768 / TN);
    }
    pipe_kernel<<<32 + nbG2 + nbG1, 512, 0, stream>>>(
        exfb[c & 1], pgbuf, mask, length, Wp1, Wp2, bp2, Whc, state, out,
        c * CS, NSc, (c == 0) ? 1 : 0,
        cfb[(c + 1) & 1], exfb[(c + 1) & 1], Wcomb, cbias, M6n, nbG2,
        memory, W1, b1, cfb[(c + 2) & 1], McfN, NS1, c01);
  }
}